// Round 1
// baseline (483.060 us; speedup 1.0000x reference)
//
#include <hip/hip_runtime.h>
#include <math.h>

#define B_SZ 8
#define L_SEQ 4096
#define H_DIM 128
#define N_STATE 64
#define LN_EPS 1e-5f

// ws layout (floats):
// [0, 8192)       z_re   (h*64+n)
// [8192, 16384)   z_im
// [16384, 24576)  cb_re
// [24576, 32768)  cb_im
// [32768, ...)    ylin   (B, L, H) f32 = conv + D*u (pre-GELU, pre-LN)

__global__ __launch_bounds__(256) void setup_tables(
    const float* __restrict__ log_neg_real, const float* __restrict__ imagp,
    const float* __restrict__ B_re, const float* __restrict__ B_im,
    const float* __restrict__ C_re, const float* __restrict__ C_im,
    const float* __restrict__ log_step, float* __restrict__ ws) {
  int i = blockIdx.x * 256 + threadIdx.x;  // i = h*64 + n
  if (i >= H_DIM * N_STATE) return;
  int h = i >> 6;
  int n = i & 63;
  float st = expf(log_step[h]);
  st = fminf(fmaxf(st, 1e-5f), 1.0f);           // clip(exp(log_step), 1e-5, 1)
  float lam_re = -expf(log_neg_real[n]);        // Lambda_re = -exp(log_neg_real)
  float sre = st * lam_re;
  float sim = st * imagp[n];
  float em = expf(sre);
  float zre = em * cosf(sim);                   // z = exp(s_re + i s_im)
  float zim = em * sinf(sim);
  float bre = B_re[i] * st;                     // Bbar = B * step
  float bim = B_im[i] * st;
  float cre = C_re[i];
  float cim = C_im[i];
  ws[i]           = zre;
  ws[8192 + i]    = zim;
  ws[16384 + i]   = cre * bre - cim * bim;      // CB_re
  ws[24576 + i]   = cre * bim + cim * bre;      // CB_im
}

// One wave per (b,h). Lane n holds state n. Sequential over L.
__global__ __launch_bounds__(256) void s4d_scan(
    const float* __restrict__ u, const float* __restrict__ ws,
    const float* __restrict__ Dp, float* __restrict__ ylin) {
  int wv = (blockIdx.x * 256 + threadIdx.x) >> 6;   // 0..1023
  int lane = threadIdx.x & 63;
  int b = wv >> 7;            // / H_DIM
  int h = wv & (H_DIM - 1);
  int idx = (h << 6) | lane;  // (h, n)

  float zre = ws[idx];
  float zim = ws[8192 + idx];
  float cre = ws[16384 + idx];
  float cim = ws[24576 + idx];
  float Dh = Dp[h];

  const float* up = u    + (size_t)b * L_SEQ * H_DIM + h;
  float*       yp = ylin + (size_t)b * L_SEQ * H_DIM + h;

  float xre = 0.0f, xim = 0.0f;
  const int T = 16;
  for (int l0 = 0; l0 < L_SEQ; l0 += T) {
    float uv[T], c[T];
    #pragma unroll
    for (int t = 0; t < T; ++t) uv[t] = up[(size_t)(l0 + t) * H_DIM];

    #pragma unroll
    for (int t = 0; t < T; ++t) {
      // x = z * x + u   (complex; nr/ni computed from old state)
      float nr = fmaf(zre, xre, fmaf(-zim, xim, uv[t]));
      float ni = fmaf(zre, xim, zim * xre);
      xre = nr; xim = ni;
      // contribution Re(CB * x)
      float contrib = fmaf(cre, xre, -(cim * xim));
      // skip term D*u added on exactly one lane (survives the sum once)
      c[t] = (lane == 0) ? fmaf(Dh, uv[t], contrib) : contrib;
    }

    // batched butterfly reduction over 64 lanes (stage-major for ILP)
    #pragma unroll
    for (int off = 32; off >= 1; off >>= 1) {
      #pragma unroll
      for (int t = 0; t < T; ++t) c[t] += __shfl_xor(c[t], off);
    }

    // lane t writes step t's result (compile-time indexed select)
    float o = c[0];
    #pragma unroll
    for (int t = 1; t < T; ++t) if (lane == t) o = c[t];
    if (lane < T) yp[(size_t)(l0 + lane) * H_DIM] = o;
  }
}

// One wave per (b,l) row of H=128: exact GELU + LayerNorm over H.
__global__ __launch_bounds__(256) void post_ln(
    const float* __restrict__ ylin, const float* __restrict__ gamma,
    const float* __restrict__ beta, float* __restrict__ out) {
  int row = blockIdx.x * 4 + (threadIdx.x >> 6);   // 0 .. B*L-1
  int lane = threadIdx.x & 63;
  size_t base = (size_t)row * H_DIM;

  float2 v = *(const float2*)(ylin + base + lane * 2);
  const float kInvSqrt2 = 0.70710678118654752f;
  float g0 = 0.5f * v.x * (1.0f + erff(v.x * kInvSqrt2));
  float g1 = 0.5f * v.y * (1.0f + erff(v.y * kInvSqrt2));

  float s  = g0 + g1;
  float ss = fmaf(g0, g0, g1 * g1);
  #pragma unroll
  for (int off = 32; off >= 1; off >>= 1) {
    s  += __shfl_xor(s,  off);
    ss += __shfl_xor(ss, off);
  }
  float mean = s * (1.0f / H_DIM);
  float var  = ss * (1.0f / H_DIM) - mean * mean;
  float inv  = rsqrtf(var + LN_EPS);

  float2 gm = *(const float2*)(gamma + lane * 2);
  float2 bt = *(const float2*)(beta + lane * 2);
  float2 o;
  o.x = (g0 - mean) * inv * gm.x + bt.x;
  o.y = (g1 - mean) * inv * gm.y + bt.y;
  *(float2*)(out + base + lane * 2) = o;
}

extern "C" void kernel_launch(void* const* d_in, const int* in_sizes, int n_in,
                              void* d_out, int out_size, void* d_ws, size_t ws_size,
                              hipStream_t stream) {
  const float* u     = (const float*)d_in[0];
  const float* lnr   = (const float*)d_in[1];
  const float* im    = (const float*)d_in[2];
  const float* Bre   = (const float*)d_in[3];
  const float* Bim   = (const float*)d_in[4];
  const float* Cre   = (const float*)d_in[5];
  const float* Cim   = (const float*)d_in[6];
  const float* D     = (const float*)d_in[7];
  const float* lstep = (const float*)d_in[8];
  const float* gamma = (const float*)d_in[9];
  const float* beta  = (const float*)d_in[10];
  float* out  = (float*)d_out;
  float* ws   = (float*)d_ws;
  float* ylin = ws + 4 * H_DIM * N_STATE;

  setup_tables<<<(H_DIM * N_STATE + 255) / 256, 256, 0, stream>>>(
      lnr, im, Bre, Bim, Cre, Cim, lstep, ws);
  s4d_scan<<<(B_SZ * H_DIM) / 4, 256, 0, stream>>>(u, ws, D, ylin);
  post_ln<<<(B_SZ * L_SEQ) / 4, 256, 0, stream>>>(ylin, gamma, beta, out);
}

// Round 2
// 389.008 us; speedup vs baseline: 1.2418x; 1.2418x over previous
//
#include <hip/hip_runtime.h>
#include <math.h>

#define B_SZ 8
#define L_SEQ 4096
#define H_DIM 128
#define N_STATE 64
#define LN_EPS 1e-5f
#define C_CHUNK 8
#define CLEN 512   // L_SEQ / C_CHUNK

// ws layout (floats):
// [0, 8192)        z_re   (h*64+n)
// [8192, 16384)    z_im
// [16384, 24576)   cb_re
// [24576, 32768)   cb_im
// [32768, 40960)   zp_re  = Re(z^CLEN)
// [40960, 49152)   zp_im  = Im(z^CLEN)
// [49152, +B*H*C*64*2) per-chunk partial final states (b,h,c,n)(re,im)
#define WS_ZIM 8192
#define WS_CBRE 16384
#define WS_CBIM 24576
#define WS_ZPRE 32768
#define WS_ZPIM 40960
#define WS_STATES 49152

__global__ __launch_bounds__(256) void setup_tables(
    const float* __restrict__ log_neg_real, const float* __restrict__ imagp,
    const float* __restrict__ B_re, const float* __restrict__ B_im,
    const float* __restrict__ C_re, const float* __restrict__ C_im,
    const float* __restrict__ log_step, float* __restrict__ ws) {
  int i = blockIdx.x * 256 + threadIdx.x;  // i = h*64 + n
  if (i >= H_DIM * N_STATE) return;
  int h = i >> 6;
  int n = i & 63;
  float st = expf(log_step[h]);
  st = fminf(fmaxf(st, 1e-5f), 1.0f);           // clip(exp(log_step), 1e-5, 1)
  float lam_re = -expf(log_neg_real[n]);        // Lambda_re = -exp(log_neg_real)
  float sre = st * lam_re;
  float sim = st * imagp[n];
  float em = expf(sre);
  float zre = em * cosf(sim);                   // z = exp(s_re + i s_im)
  float zim = em * sinf(sim);
  float bre = B_re[i] * st;                     // Bbar = B * step
  float bim = B_im[i] * st;
  float cre = C_re[i];
  float cim = C_im[i];
  ws[i]            = zre;
  ws[WS_ZIM + i]   = zim;
  ws[WS_CBRE + i]  = cre * bre - cim * bim;     // CB_re
  ws[WS_CBIM + i]  = cre * bim + cim * bre;     // CB_im
  // z^CLEN = exp(CLEN*s_re) * (cos(CLEN*s_im) + i sin(CLEN*s_im))
  float pm = expf((float)CLEN * sre);
  ws[WS_ZPRE + i]  = pm * cosf((float)CLEN * sim);
  ws[WS_ZPIM + i]  = pm * sinf((float)CLEN * sim);
}

// Phase 1: one wave per (b,h,c); scan chunk c from zero state, store final state.
__global__ __launch_bounds__(256) void s4d_phase1(
    const float* __restrict__ u, float* __restrict__ ws) {
  int wv = (blockIdx.x * 256 + threadIdx.x) >> 6;   // 0..8191 = ((b*H+h)*C + c)
  int lane = threadIdx.x & 63;
  int c  = wv & (C_CHUNK - 1);
  int bh = wv >> 3;
  int h  = bh & (H_DIM - 1);
  int b  = bh >> 7;
  int idx = (h << 6) | lane;

  float zre = ws[idx];
  float zim = ws[WS_ZIM + idx];
  const float* up = u + ((size_t)b * L_SEQ + (size_t)c * CLEN) * H_DIM + h;

  float xre = 0.0f, xim = 0.0f;
  for (int l0 = 0; l0 < CLEN; l0 += 16) {
    float uv[16];
    #pragma unroll
    for (int t = 0; t < 16; ++t) uv[t] = up[(size_t)(l0 + t) * H_DIM];
    #pragma unroll
    for (int t = 0; t < 16; ++t) {
      float nr = fmaf(zre, xre, fmaf(-zim, xim, uv[t]));
      float ni = fmaf(zre, xim, zim * xre);
      xre = nr; xim = ni;
    }
  }
  size_t sidx = WS_STATES + ((size_t)wv * 64 + lane) * 2;
  ws[sidx]     = xre;
  ws[sidx + 1] = xim;
}

// Phase 3: one wave per (b,h,c); rebuild init state from prior chunks' partial
// states, then scan chunk producing y = conv + D*u into ylin (= d_out).
__global__ __launch_bounds__(256) void s4d_phase3(
    const float* __restrict__ u, const float* __restrict__ ws,
    const float* __restrict__ Dp, float* __restrict__ ylin) {
  int wv = (blockIdx.x * 256 + threadIdx.x) >> 6;   // ((b*H+h)*C + c)
  int lane = threadIdx.x & 63;
  int c  = wv & (C_CHUNK - 1);
  int bh = wv >> 3;
  int h  = bh & (H_DIM - 1);
  int b  = bh >> 7;
  int idx = (h << 6) | lane;

  float zre = ws[idx];
  float zim = ws[WS_ZIM + idx];
  float cre = ws[WS_CBRE + idx];
  float cim = ws[WS_CBIM + idx];
  float Dh  = Dp[h];

  // X_init(c) = sum_{j<c} (z^CLEN)^{c-1-j} * S(j)  via Horner
  float xre = 0.0f, xim = 0.0f;
  if (c > 0) {
    float zpre = ws[WS_ZPRE + idx];
    float zpim = ws[WS_ZPIM + idx];
    for (int j = 0; j < c; ++j) {
      size_t sidx = WS_STATES + (((size_t)bh * C_CHUNK + j) * 64 + lane) * 2;
      float sre = ws[sidx], sim = ws[sidx + 1];
      float nr = fmaf(zpre, xre, fmaf(-zpim, xim, sre));
      float ni = fmaf(zpre, xim, fmaf(zpim, xre, sim));
      xre = nr; xim = ni;
    }
  }

  const float* up = u    + ((size_t)b * L_SEQ + (size_t)c * CLEN) * H_DIM + h;
  float*       yp = ylin + ((size_t)b * L_SEQ + (size_t)c * CLEN) * H_DIM + h;

  const int T = 16;
  for (int l0 = 0; l0 < CLEN; l0 += T) {
    float uv[T], cc[T];
    #pragma unroll
    for (int t = 0; t < T; ++t) uv[t] = up[(size_t)(l0 + t) * H_DIM];

    #pragma unroll
    for (int t = 0; t < T; ++t) {
      float nr = fmaf(zre, xre, fmaf(-zim, xim, uv[t]));
      float ni = fmaf(zre, xim, zim * xre);
      xre = nr; xim = ni;
      float contrib = fmaf(cre, xre, -(cim * xim));
      cc[t] = (lane == 0) ? fmaf(Dh, uv[t], contrib) : contrib;
    }

    #pragma unroll
    for (int off = 32; off >= 1; off >>= 1) {
      #pragma unroll
      for (int t = 0; t < T; ++t) cc[t] += __shfl_xor(cc[t], off);
    }

    float o = cc[0];
    #pragma unroll
    for (int t = 1; t < T; ++t) if (lane == t) o = cc[t];
    if (lane < T) yp[(size_t)(l0 + lane) * H_DIM] = o;
  }
}

// One wave per (b,l) row of H=128: exact GELU + LayerNorm over H. In-place on d_out.
__global__ __launch_bounds__(256) void post_ln(
    const float* __restrict__ ylin, const float* __restrict__ gamma,
    const float* __restrict__ beta, float* __restrict__ out) {
  int row = blockIdx.x * 4 + (threadIdx.x >> 6);   // 0 .. B*L-1
  int lane = threadIdx.x & 63;
  size_t base = (size_t)row * H_DIM;

  float2 v = *(const float2*)(ylin + base + lane * 2);
  const float kInvSqrt2 = 0.70710678118654752f;
  float g0 = 0.5f * v.x * (1.0f + erff(v.x * kInvSqrt2));
  float g1 = 0.5f * v.y * (1.0f + erff(v.y * kInvSqrt2));

  float s  = g0 + g1;
  float ss = fmaf(g0, g0, g1 * g1);
  #pragma unroll
  for (int off = 32; off >= 1; off >>= 1) {
    s  += __shfl_xor(s,  off);
    ss += __shfl_xor(ss, off);
  }
  float mean = s * (1.0f / H_DIM);
  float var  = ss * (1.0f / H_DIM) - mean * mean;
  float inv  = rsqrtf(var + LN_EPS);

  float2 gm = *(const float2*)(gamma + lane * 2);
  float2 bt = *(const float2*)(beta + lane * 2);
  float2 o;
  o.x = (g0 - mean) * inv * gm.x + bt.x;
  o.y = (g1 - mean) * inv * gm.y + bt.y;
  *(float2*)(out + base + lane * 2) = o;
}

extern "C" void kernel_launch(void* const* d_in, const int* in_sizes, int n_in,
                              void* d_out, int out_size, void* d_ws, size_t ws_size,
                              hipStream_t stream) {
  const float* u     = (const float*)d_in[0];
  const float* lnr   = (const float*)d_in[1];
  const float* im    = (const float*)d_in[2];
  const float* Bre   = (const float*)d_in[3];
  const float* Bim   = (const float*)d_in[4];
  const float* Cre   = (const float*)d_in[5];
  const float* Cim   = (const float*)d_in[6];
  const float* D     = (const float*)d_in[7];
  const float* lstep = (const float*)d_in[8];
  const float* gamma = (const float*)d_in[9];
  const float* beta  = (const float*)d_in[10];
  float* out = (float*)d_out;
  float* ws  = (float*)d_ws;

  setup_tables<<<(H_DIM * N_STATE + 255) / 256, 256, 0, stream>>>(
      lnr, im, Bre, Bim, Cre, Cim, lstep, ws);
  // 8192 waves, 4 waves/block
  s4d_phase1<<<(B_SZ * H_DIM * C_CHUNK) / 4, 256, 0, stream>>>(u, ws);
  s4d_phase3<<<(B_SZ * H_DIM * C_CHUNK) / 4, 256, 0, stream>>>(u, ws, D, out);
  post_ln<<<(B_SZ * L_SEQ) / 4, 256, 0, stream>>>(out, gamma, beta, out);
}

// Round 3
// 200.990 us; speedup vs baseline: 2.4034x; 1.9355x over previous
//
#include <hip/hip_runtime.h>
#include <hip/hip_bf16.h>
#include <math.h>

#define B_SZ 8
#define L_SEQ 4096
#define H_DIM 128
#define N_STATE 64
#define LN_EPS 1e-5f
#define C_CHUNK 8
#define CLEN 512   // L_SEQ / C_CHUNK

// ws layout (float offsets):
// [0, 8192)        z_re   (h*64+n)
// [8192, 16384)    z_im
// [16384, 24576)   cb_re
// [24576, 32768)   cb_im
// [32768, 40960)   zp_re  = Re(z^CLEN)
// [40960, 49152)   zp_im  = Im(z^CLEN)
// [49152, 49152+1048576)  per-chunk final states (b,h,c,n)(re,im) f32
// [1097728, +2097152)     ylin (b,h,l) bf16 (as ushort)  -- total 12.8 MB
#define WS_ZIM 8192
#define WS_CBRE 16384
#define WS_CBIM 24576
#define WS_ZPRE 32768
#define WS_ZPIM 40960
#define WS_STATES 49152
#define WS_YLIN (49152 + 1048576)

__global__ __launch_bounds__(256) void setup_tables(
    const float* __restrict__ log_neg_real, const float* __restrict__ imagp,
    const float* __restrict__ B_re, const float* __restrict__ B_im,
    const float* __restrict__ C_re, const float* __restrict__ C_im,
    const float* __restrict__ log_step, float* __restrict__ ws) {
  int i = blockIdx.x * 256 + threadIdx.x;  // i = h*64 + n
  if (i >= H_DIM * N_STATE) return;
  int h = i >> 6;
  float st = expf(log_step[h]);
  st = fminf(fmaxf(st, 1e-5f), 1.0f);
  float lam_re = -expf(log_neg_real[i & 63]);
  float sre = st * lam_re;
  float sim = st * imagp[i & 63];
  float em = expf(sre);
  float zre = em * cosf(sim);
  float zim = em * sinf(sim);
  float bre = B_re[i] * st;
  float bim = B_im[i] * st;
  float cre = C_re[i];
  float cim = C_im[i];
  ws[i]           = zre;
  ws[WS_ZIM + i]  = zim;
  ws[WS_CBRE + i] = cre * bre - cim * bim;
  ws[WS_CBIM + i] = cre * bim + cim * bre;
  float pm = expf((float)CLEN * sre);
  ws[WS_ZPRE + i] = pm * cosf((float)CLEN * sim);
  ws[WS_ZPIM + i] = pm * sinf((float)CLEN * sim);
}

// Phase 1: one wave per (b,h,c), c<7; scan chunk from zero state, store final state.
__global__ __launch_bounds__(256) void s4d_phase1(
    const float* __restrict__ u, float* __restrict__ ws) {
  int wv = (blockIdx.x * 256 + threadIdx.x) >> 6;   // ((b*H+h)*C + c)
  int lane = threadIdx.x & 63;
  int c  = wv & (C_CHUNK - 1);
  if (c == C_CHUNK - 1) return;                     // last chunk's state unused
  int bh = wv >> 3;
  int h  = bh & (H_DIM - 1);
  int b  = bh >> 7;
  int idx = (h << 6) | lane;

  float zre = ws[idx];
  float zim = ws[WS_ZIM + idx];
  const float* up = u + ((size_t)b * L_SEQ + (size_t)c * CLEN) * H_DIM + h;

  float xre = 0.0f, xim = 0.0f;
  #pragma unroll 1
  for (int l0 = 0; l0 < CLEN; l0 += 16) {
    float uv[16];
    #pragma unroll
    for (int t = 0; t < 16; ++t) uv[t] = up[(size_t)(l0 + t) * H_DIM];
    #pragma unroll
    for (int t = 0; t < 16; ++t) {
      float nr = fmaf(zre, xre, fmaf(-zim, xim, uv[t]));
      float ni = fmaf(zre, xim, zim * xre);
      xre = nr; xim = ni;
    }
  }
  size_t sidx = WS_STATES + ((size_t)wv * 64 + lane) * 2;
  ws[sidx]     = xre;
  ws[sidx + 1] = xim;
}

// Phase 3: one wave per (b,h,c); Horner prologue for init state, then scan chunk
// writing y = conv + D*u into ylin (b,h,l) as bf16. Reduction: value-packed
// butterfly (permlane32/16_swap = VALU; only 5 DS ops per 16 outputs).
__global__ __launch_bounds__(256) void s4d_phase3(
    const float* __restrict__ u, const float* __restrict__ ws,
    const float* __restrict__ Dp, unsigned short* __restrict__ ylin) {
  int wv = (blockIdx.x * 256 + threadIdx.x) >> 6;   // ((b*H+h)*C + c)
  int lane = threadIdx.x & 63;
  int c  = wv & (C_CHUNK - 1);
  int bh = wv >> 3;
  int h  = bh & (H_DIM - 1);
  int b  = bh >> 7;
  int idx = (h << 6) | lane;

  float zre = ws[idx];
  float zim = ws[WS_ZIM + idx];
  float cre = ws[WS_CBRE + idx];
  float cim = ws[WS_CBIM + idx];
  float du  = (lane == 0) ? Dp[h] : 0.0f;   // skip term counted once in the sum

  // X_init(c) = sum_{j<c} (z^CLEN)^{c-1-j} * S(j)  via Horner
  float xre = 0.0f, xim = 0.0f;
  if (c > 0) {
    float zpre = ws[WS_ZPRE + idx];
    float zpim = ws[WS_ZPIM + idx];
    for (int j = 0; j < c; ++j) {
      size_t sidx = WS_STATES + (((size_t)bh * C_CHUNK + j) * 64 + lane) * 2;
      float sre = ws[sidx], sim = ws[sidx + 1];
      float nr = fmaf(zpre, xre, fmaf(-zpim, xim, sre));
      float ni = fmaf(zpre, xim, fmaf(zpim, xre, sim));
      xre = nr; xim = ni;
    }
  }

  const float* up = u + ((size_t)b * L_SEQ + (size_t)c * CLEN) * H_DIM + h;
  unsigned short* yp = ylin + (size_t)bh * L_SEQ + (size_t)c * CLEN;

  #pragma unroll 1
  for (int l0 = 0; l0 < CLEN; l0 += 16) {
    float uv[16], cc[16];
    #pragma unroll
    for (int t = 0; t < 16; ++t) uv[t] = up[(size_t)(l0 + t) * H_DIM];

    #pragma unroll
    for (int t = 0; t < 16; ++t) {
      float nr = fmaf(zre, xre, fmaf(-zim, xim, uv[t]));
      float ni = fmaf(zre, xim, zim * xre);
      xre = nr; xim = ni;
      float contrib = fmaf(cre, xre, -(cim * xim));
      cc[t] = fmaf(du, uv[t], contrib);
    }

    // ---- value-packed 64-lane reduction of 16 values ----
    // stage xor32: permlane32_swap (VALU). d[t]: bit5 of lane selects cc[t] vs cc[t+8]
    float d[8];
    #pragma unroll
    for (int t = 0; t < 8; ++t) {
      float a = cc[t], bb = cc[t + 8];
      asm("v_permlane32_swap_b32 %0, %1" : "+v"(a), "+v"(bb));
      d[t] = a + bb;
    }
    // stage xor16: permlane16_swap. e[t]: idx = t + 4*b4 + 8*b5
    float e[4];
    #pragma unroll
    for (int t = 0; t < 4; ++t) {
      float a = d[t], bb = d[t + 4];
      asm("v_permlane16_swap_b32 %0, %1" : "+v"(a), "+v"(bb));
      e[t] = a + bb;
    }
    // stage xor8 (pack via select+shuffle): f[t]: idx = t + 2*b3 + 4*b4 + 8*b5
    float f[2];
    #pragma unroll
    for (int t = 0; t < 2; ++t) {
      bool hi = (lane & 8) != 0;
      float send = hi ? e[t] : e[t + 2];
      float recv = __shfl_xor(send, 8);
      f[t] = (hi ? e[t + 2] : e[t]) + recv;
    }
    // stage xor4: g: idx = (lane>>2)&15
    float g;
    {
      bool hi = (lane & 4) != 0;
      float send = hi ? f[0] : f[1];
      float recv = __shfl_xor(send, 4);
      g = (hi ? f[1] : f[0]) + recv;
    }
    g += __shfl_xor(g, 2);
    g += __shfl_xor(g, 1);
    // lane 4t holds output t; one contiguous 32B bf16 store per tile
    if ((lane & 3) == 0) {
      yp[l0 + (lane >> 2)] = __bfloat16_as_ushort(__float2bfloat16(g));
    }
  }
}

// post_ln: block = (b, 32-l tile). Load 128h x 32l bf16 tile coalesced,
// GELU into LDS (stride 33, conflict-free columns), wave-per-l LN, coalesced out.
__global__ __launch_bounds__(256) void post_ln_t(
    const unsigned short* __restrict__ ylin, const float* __restrict__ gamma,
    const float* __restrict__ beta, float* __restrict__ out) {
  __shared__ float gbuf[H_DIM][33];
  int blk = blockIdx.x;           // b*(L/32) + lt
  int b = blk >> 7;
  int l0 = (blk & 127) * 32;
  int t = threadIdx.x;
  const float kInvSqrt2 = 0.70710678118654752f;

  #pragma unroll
  for (int p = 0; p < 4; ++p) {
    int h = p * 32 + (t >> 3);
    int c4 = (t & 7) * 4;
    const unsigned short* src = ylin + ((size_t)(b * H_DIM + h) << 12) + l0 + c4;
    uint2 v = *(const uint2*)src;   // 4 bf16
    float y0 = __uint_as_float((v.x & 0xffffu) << 16);
    float y1 = __uint_as_float(v.x & 0xffff0000u);
    float y2 = __uint_as_float((v.y & 0xffffu) << 16);
    float y3 = __uint_as_float(v.y & 0xffff0000u);
    gbuf[h][c4 + 0] = 0.5f * y0 * (1.0f + erff(y0 * kInvSqrt2));
    gbuf[h][c4 + 1] = 0.5f * y1 * (1.0f + erff(y1 * kInvSqrt2));
    gbuf[h][c4 + 2] = 0.5f * y2 * (1.0f + erff(y2 * kInvSqrt2));
    gbuf[h][c4 + 3] = 0.5f * y3 * (1.0f + erff(y3 * kInvSqrt2));
  }
  __syncthreads();

  int w = t >> 6, lane = t & 63;
  float2 gm = *(const float2*)(gamma + lane * 2);
  float2 bt = *(const float2*)(beta + lane * 2);
  #pragma unroll 1
  for (int j = 0; j < 8; ++j) {
    int l = w * 8 + j;
    float g0 = gbuf[2 * lane][l];
    float g1 = gbuf[2 * lane + 1][l];
    float s  = g0 + g1;
    float ss = fmaf(g0, g0, g1 * g1);
    #pragma unroll
    for (int off = 32; off >= 1; off >>= 1) {
      s  += __shfl_xor(s,  off);
      ss += __shfl_xor(ss, off);
    }
    float mean = s * (1.0f / H_DIM);
    float var  = ss * (1.0f / H_DIM) - mean * mean;
    float inv  = rsqrtf(var + LN_EPS);
    float2 o;
    o.x = (g0 - mean) * inv * gm.x + bt.x;
    o.y = (g1 - mean) * inv * gm.y + bt.y;
    *(float2*)(out + ((size_t)(b * L_SEQ + l0 + l)) * H_DIM + lane * 2) = o;
  }
}

extern "C" void kernel_launch(void* const* d_in, const int* in_sizes, int n_in,
                              void* d_out, int out_size, void* d_ws, size_t ws_size,
                              hipStream_t stream) {
  const float* u     = (const float*)d_in[0];
  const float* lnr   = (const float*)d_in[1];
  const float* im    = (const float*)d_in[2];
  const float* Bre   = (const float*)d_in[3];
  const float* Bim   = (const float*)d_in[4];
  const float* Cre   = (const float*)d_in[5];
  const float* Cim   = (const float*)d_in[6];
  const float* D     = (const float*)d_in[7];
  const float* lstep = (const float*)d_in[8];
  const float* gamma = (const float*)d_in[9];
  const float* beta  = (const float*)d_in[10];
  float* out = (float*)d_out;
  float* ws  = (float*)d_ws;
  unsigned short* ylin = (unsigned short*)(ws + WS_YLIN);

  setup_tables<<<(H_DIM * N_STATE + 255) / 256, 256, 0, stream>>>(
      lnr, im, Bre, Bim, Cre, Cim, lstep, ws);
  s4d_phase1<<<(B_SZ * H_DIM * C_CHUNK) / 4, 256, 0, stream>>>(u, ws);
  s4d_phase3<<<(B_SZ * H_DIM * C_CHUNK) / 4, 256, 0, stream>>>(u, ws, D, ylin);
  post_ln_t<<<B_SZ * (L_SEQ / 32), 256, 0, stream>>>(ylin, gamma, beta, out);
}

// Round 4
// 192.949 us; speedup vs baseline: 2.5036x; 1.0417x over previous
//
#include <hip/hip_runtime.h>
#include <hip/hip_bf16.h>
#include <math.h>

#define B_SZ 8
#define L_SEQ 4096
#define H_DIM 128
#define N_STATE 64
#define LN_EPS 1e-5f
#define C_CHUNK 8
#define CLEN 512   // L_SEQ / C_CHUNK

// ws layout (float offsets):
// [0, 8192)        z_re   (h*64+n)
// [8192, 16384)    z_im
// [16384, 24576)   cb_re
// [24576, 32768)   cb_im
// [32768, 40960)   zp_re  = Re(z^CLEN)
// [40960, 49152)   zp_im  = Im(z^CLEN)
// [49152, +1048576)  per-chunk final states (b,h,c,n)(re,im) f32
// [1097728, +2097152) ylin (b,h,l) bf16 (ushort)   => total 12.8 MB
// d_out is reused as scratch for u transposed to (b,h,l) f32 (16.8 MB),
// then overwritten by post_ln_t with the final output.
#define WS_ZIM 8192
#define WS_CBRE 16384
#define WS_CBIM 24576
#define WS_ZPRE 32768
#define WS_ZPIM 40960
#define WS_STATES 49152
#define WS_YLIN (49152 + 1048576)

// ---- value-packed butterfly helpers (swap is 1 VALU op; no tied-asm movs) ----
__device__ __forceinline__ float plswap32_sum(float a, float b) {
#if __has_builtin(__builtin_amdgcn_permlane32_swap)
  auto r = __builtin_amdgcn_permlane32_swap(__float_as_uint(a), __float_as_uint(b),
                                            false, false);
  return __uint_as_float(r[0]) + __uint_as_float(r[1]);
#else
  asm("v_permlane32_swap_b32 %0, %1" : "+v"(a), "+v"(b));
  return a + b;
#endif
}
__device__ __forceinline__ float plswap16_sum(float a, float b) {
#if __has_builtin(__builtin_amdgcn_permlane16_swap)
  auto r = __builtin_amdgcn_permlane16_swap(__float_as_uint(a), __float_as_uint(b),
                                            false, false);
  return __uint_as_float(r[0]) + __uint_as_float(r[1]);
#else
  asm("v_permlane16_swap_b32 %0, %1" : "+v"(a), "+v"(b));
  return a + b;
#endif
}

__global__ __launch_bounds__(256) void setup_tables(
    const float* __restrict__ log_neg_real, const float* __restrict__ imagp,
    const float* __restrict__ B_re, const float* __restrict__ B_im,
    const float* __restrict__ C_re, const float* __restrict__ C_im,
    const float* __restrict__ log_step, float* __restrict__ ws) {
  int i = blockIdx.x * 256 + threadIdx.x;  // i = h*64 + n
  if (i >= H_DIM * N_STATE) return;
  int h = i >> 6;
  float st = expf(log_step[h]);
  st = fminf(fmaxf(st, 1e-5f), 1.0f);
  float lam_re = -expf(log_neg_real[i & 63]);
  float sre = st * lam_re;
  float sim = st * imagp[i & 63];
  float em = expf(sre);
  float zre = em * cosf(sim);
  float zim = em * sinf(sim);
  float bre = B_re[i] * st;
  float bim = B_im[i] * st;
  float cre = C_re[i];
  float cim = C_im[i];
  ws[i]           = zre;
  ws[WS_ZIM + i]  = zim;
  ws[WS_CBRE + i] = cre * bre - cim * bim;
  ws[WS_CBIM + i] = cre * bim + cim * bre;
  float pm = expf((float)CLEN * sre);
  ws[WS_ZPRE + i] = pm * cosf((float)CLEN * sim);
  ws[WS_ZPIM + i] = pm * sinf((float)CLEN * sim);
}

// (b,l,h) -> (b,h,l) f32 transpose, 64x64 tiles via LDS.
__global__ __launch_bounds__(256) void transpose_u(
    const float* __restrict__ u, float* __restrict__ ut) {
  __shared__ float tile[64][65];
  int blk = blockIdx.x;            // b*128 + ht*64 + lt
  int b  = blk >> 7;
  int ht = (blk >> 6) & 1;
  int lt = blk & 63;
  int t = threadIdx.x;
  int l0 = lt * 64, h0 = ht * 64;
  #pragma unroll
  for (int p = 0; p < 16; ++p) {
    int ll = p * 4 + (t >> 6);
    int hh = t & 63;
    tile[ll][hh] = u[((size_t)(b * L_SEQ + l0 + ll)) * H_DIM + h0 + hh];
  }
  __syncthreads();
  #pragma unroll
  for (int p = 0; p < 16; ++p) {
    int hh = p * 4 + (t >> 6);
    int ll = t & 63;
    ut[(((size_t)(b * H_DIM + h0 + hh)) << 12) + l0 + ll] = tile[ll][hh];
  }
}

// Phase 1: one wave per (b,h,c), c<7; scan chunk from zero state, store final state.
// u reads are wave-uniform + contiguous -> scalar s_load path.
__global__ __launch_bounds__(256) void s4d_phase1(
    const float* __restrict__ ut, float* __restrict__ ws) {
  int t = threadIdx.x;
  int wv = __builtin_amdgcn_readfirstlane((int)(blockIdx.x * 4) + (t >> 6));
  int lane = t & 63;
  int c = wv & (C_CHUNK - 1);
  if (c == C_CHUNK - 1) return;                 // last chunk's state unused
  int bh = wv >> 3;
  int h  = bh & (H_DIM - 1);
  int idx = (h << 6) | lane;

  float zre = ws[idx];
  float zim = ws[WS_ZIM + idx];
  const float* up = ut + (((size_t)bh) << 12) + c * CLEN;

  float xre = 0.0f, xim = 0.0f;
  #pragma unroll 1
  for (int l0 = 0; l0 < CLEN; l0 += 16) {
    float uv[16];
    #pragma unroll
    for (int tt = 0; tt < 16; ++tt) uv[tt] = up[l0 + tt];
    #pragma unroll
    for (int tt = 0; tt < 16; ++tt) {
      float nr = fmaf(zre, xre, fmaf(-zim, xim, uv[tt]));
      float ni = fmaf(zre, xim, zim * xre);
      xre = nr; xim = ni;
    }
  }
  size_t sidx = WS_STATES + ((size_t)wv * 64 + lane) * 2;
  ws[sidx]     = xre;
  ws[sidx + 1] = xim;
}

// Phase 3: one wave per (b,h,c); Horner init-state prologue, then scan chunk
// writing y = conv (no skip term) to ylin (b,h,l) bf16.
__global__ __launch_bounds__(256) void s4d_phase3(
    const float* __restrict__ ut, const float* __restrict__ ws,
    unsigned short* __restrict__ ylin) {
  int t = threadIdx.x;
  int wv = __builtin_amdgcn_readfirstlane((int)(blockIdx.x * 4) + (t >> 6));
  int lane = t & 63;
  int c  = wv & (C_CHUNK - 1);
  int bh = wv >> 3;
  int h  = bh & (H_DIM - 1);
  int idx = (h << 6) | lane;

  float zre = ws[idx];
  float zim = ws[WS_ZIM + idx];
  float cre = ws[WS_CBRE + idx];
  float cim = ws[WS_CBIM + idx];

  // X_init(c) = sum_{j<c} (z^CLEN)^{c-1-j} * S(j) via Horner
  float xre = 0.0f, xim = 0.0f;
  if (c > 0) {
    float zpre = ws[WS_ZPRE + idx];
    float zpim = ws[WS_ZPIM + idx];
    for (int j = 0; j < c; ++j) {
      size_t sidx = WS_STATES + (((size_t)bh * C_CHUNK + j) * 64 + lane) * 2;
      float sre = ws[sidx], sim = ws[sidx + 1];
      float nr = fmaf(zpre, xre, fmaf(-zpim, xim, sre));
      float ni = fmaf(zpre, xim, fmaf(zpim, xre, sim));
      xre = nr; xim = ni;
    }
  }

  const float* up = ut + (((size_t)bh) << 12) + c * CLEN;
  unsigned short* yp = ylin + (((size_t)bh) << 12) + c * CLEN;

  #pragma unroll 1
  for (int l0 = 0; l0 < CLEN; l0 += 16) {
    float uv[16], cc[16];
    #pragma unroll
    for (int tt = 0; tt < 16; ++tt) uv[tt] = up[l0 + tt];

    #pragma unroll
    for (int tt = 0; tt < 16; ++tt) {
      float nr = fmaf(zre, xre, fmaf(-zim, xim, uv[tt]));
      float ni = fmaf(zre, xim, zim * xre);
      xre = nr; xim = ni;
      cc[tt] = fmaf(cre, xre, -(cim * xim));
    }

    // ---- value-packed 64-lane reduction of 16 values ----
    float d[8];
    #pragma unroll
    for (int k = 0; k < 8; ++k) d[k] = plswap32_sum(cc[k], cc[k + 8]);
    float e[4];
    #pragma unroll
    for (int k = 0; k < 4; ++k) e[k] = plswap16_sum(d[k], d[k + 4]);
    float f[2];
    #pragma unroll
    for (int k = 0; k < 2; ++k) {
      bool hi = (lane & 8) != 0;
      float send = hi ? e[k] : e[k + 2];
      float recv = __shfl_xor(send, 8);
      f[k] = (hi ? e[k + 2] : e[k]) + recv;
    }
    float g;
    {
      bool hi = (lane & 4) != 0;
      float send = hi ? f[0] : f[1];
      float recv = __shfl_xor(send, 4);
      g = (hi ? f[1] : f[0]) + recv;
    }
    g += __shfl_xor(g, 2);
    g += __shfl_xor(g, 1);
    if ((lane & 3) == 0) {
      yp[l0 + (lane >> 2)] = __bfloat16_as_ushort(__float2bfloat16(g));
    }
  }
}

// post_ln: block = (b, 32-l tile). Load 128h x 32l bf16 conv tile coalesced into
// LDS; per (b,l): add D*u (f32, coalesced), exact GELU, LN over H, coalesced out.
__global__ __launch_bounds__(256) void post_ln_t(
    const unsigned short* __restrict__ ylin, const float* __restrict__ u,
    const float* __restrict__ Dp, const float* __restrict__ gamma,
    const float* __restrict__ beta, float* __restrict__ out) {
  __shared__ float ybuf[H_DIM][33];
  int blk = blockIdx.x;           // b*(L/32) + lt
  int b = blk >> 7;
  int l0 = (blk & 127) * 32;
  int t = threadIdx.x;

  #pragma unroll
  for (int p = 0; p < 4; ++p) {
    int h = p * 32 + (t >> 3);
    int c4 = (t & 7) * 4;
    const unsigned short* src = ylin + (((size_t)(b * H_DIM + h)) << 12) + l0 + c4;
    uint2 v = *(const uint2*)src;   // 4 bf16
    ybuf[h][c4 + 0] = __uint_as_float((v.x & 0xffffu) << 16);
    ybuf[h][c4 + 1] = __uint_as_float(v.x & 0xffff0000u);
    ybuf[h][c4 + 2] = __uint_as_float((v.y & 0xffffu) << 16);
    ybuf[h][c4 + 3] = __uint_as_float(v.y & 0xffff0000u);
  }
  __syncthreads();

  int w = t >> 6, lane = t & 63;
  float2 gm = *(const float2*)(gamma + lane * 2);
  float2 bt = *(const float2*)(beta + lane * 2);
  float2 dd = *(const float2*)(Dp + lane * 2);
  const float kInvSqrt2 = 0.70710678118654752f;
  #pragma unroll 1
  for (int j = 0; j < 8; ++j) {
    int l = w * 8 + j;
    float2 uu = *(const float2*)(u + ((size_t)(b * L_SEQ + l0 + l)) * H_DIM + lane * 2);
    float y0 = fmaf(dd.x, uu.x, ybuf[2 * lane][l]);
    float y1 = fmaf(dd.y, uu.y, ybuf[2 * lane + 1][l]);
    float g0 = 0.5f * y0 * (1.0f + erff(y0 * kInvSqrt2));
    float g1 = 0.5f * y1 * (1.0f + erff(y1 * kInvSqrt2));
    float s  = g0 + g1;
    float ss = fmaf(g0, g0, g1 * g1);
    #pragma unroll
    for (int off = 32; off >= 1; off >>= 1) {
      s  += __shfl_xor(s,  off);
      ss += __shfl_xor(ss, off);
    }
    float mean = s * (1.0f / H_DIM);
    float var  = ss * (1.0f / H_DIM) - mean * mean;
    float inv  = rsqrtf(var + LN_EPS);
    float2 o;
    o.x = (g0 - mean) * inv * gm.x + bt.x;
    o.y = (g1 - mean) * inv * gm.y + bt.y;
    *(float2*)(out + ((size_t)(b * L_SEQ + l0 + l)) * H_DIM + lane * 2) = o;
  }
}

extern "C" void kernel_launch(void* const* d_in, const int* in_sizes, int n_in,
                              void* d_out, int out_size, void* d_ws, size_t ws_size,
                              hipStream_t stream) {
  const float* u     = (const float*)d_in[0];
  const float* lnr   = (const float*)d_in[1];
  const float* im    = (const float*)d_in[2];
  const float* Bre   = (const float*)d_in[3];
  const float* Bim   = (const float*)d_in[4];
  const float* Cre   = (const float*)d_in[5];
  const float* Cim   = (const float*)d_in[6];
  const float* D     = (const float*)d_in[7];
  const float* lstep = (const float*)d_in[8];
  const float* gamma = (const float*)d_in[9];
  const float* beta  = (const float*)d_in[10];
  float* out = (float*)d_out;
  float* ws  = (float*)d_ws;
  unsigned short* ylin = (unsigned short*)(ws + WS_YLIN);
  float* ut = out;   // d_out doubles as transposed-u scratch, overwritten at the end

  setup_tables<<<(H_DIM * N_STATE + 255) / 256, 256, 0, stream>>>(
      lnr, im, Bre, Bim, Cre, Cim, lstep, ws);
  transpose_u<<<B_SZ * 2 * (L_SEQ / 64), 256, 0, stream>>>(u, ut);
  s4d_phase1<<<(B_SZ * H_DIM * C_CHUNK) / 4, 256, 0, stream>>>(ut, ws);
  s4d_phase3<<<(B_SZ * H_DIM * C_CHUNK) / 4, 256, 0, stream>>>(ut, ws, ylin);
  post_ln_t<<<B_SZ * (L_SEQ / 32), 256, 0, stream>>>(ylin, u, D, gamma, beta, out);
}

// Round 5
// 142.771 us; speedup vs baseline: 3.3835x; 1.3515x over previous
//
#include <hip/hip_runtime.h>
#include <hip/hip_bf16.h>
#include <math.h>

#define B_SZ 8
#define L_SEQ 4096
#define H_DIM 128
#define N_STATE 64
#define LN_EPS 1e-5f
#define NCHUNK 64
#define CLEN 64

typedef __attribute__((ext_vector_type(8))) short short8;
typedef __attribute__((ext_vector_type(4))) float f32x4;

// ---------------- ws layout (byte offsets) ----------------
// UT      @ 0        : (b,h,l) bf16, 8 MB  (overwritten in-place with ylin by s4d_mfma)
// PAR_SRE @ 8388608  : f32[8192]   (h*64+n)  s_re = step*Lambda_re
// PAR_SIM @ +32768   : f32[8192]   s_im = step*imag
// PAR_CBR @ +65536   : f32[8192]   CB_re
// PAR_CBI @ +98304   : f32[8192]   CB_im
// Z64     @ 8519680  : f32[8192*2] z^64 (re,im)
// KBUF    @ 8585216  : f32[8192]   K[h][d], d<64
// TBL     @ 8617984  : 5 bf16 tables, each 524288 ushorts (1 MB), frag-swizzled:
//   entry id = ((h*4 + blk)*2 + kt)*64 + lane, 8 values each (j=0..7)
//   W_RE +0, W_IM +524288, TT +1048576, M_RE +1572864, M_NIM +2097152 (ushort offs)
#define UT_OFF    0
#define PAR_OFF   8388608
#define Z64_OFF   8519680
#define KBUF_OFF  8585216
#define TBL_OFF   8617984
#define WRE_E     0
#define WIM_E     524288
#define TT_E      1048576
#define MRE_E     1572864
#define MNIM_E    2097152

__device__ __forceinline__ unsigned short bfbits(float f) {
  return __bfloat16_as_ushort(__float2bfloat16(f));
}
__device__ __forceinline__ f32x4 mfma16(short8 a, short8 b, f32x4 c) {
  return __builtin_amdgcn_mfma_f32_16x16x32_bf16(a, b, c, 0, 0, 0);
}

// setup1: per (h,n) recurrence params + z^64.
__global__ __launch_bounds__(256) void setup_par(
    const float* __restrict__ log_neg_real, const float* __restrict__ imagp,
    const float* __restrict__ B_re, const float* __restrict__ B_im,
    const float* __restrict__ C_re, const float* __restrict__ C_im,
    const float* __restrict__ log_step, char* __restrict__ wsb) {
  int i = blockIdx.x * 256 + threadIdx.x;  // h*64+n
  if (i >= H_DIM * N_STATE) return;
  float* sre_a = (float*)(wsb + PAR_OFF);
  float* sim_a = sre_a + 8192;
  float* cbr_a = sre_a + 16384;
  float* cbi_a = sre_a + 24576;
  float* z64_a = (float*)(wsb + Z64_OFF);
  int h = i >> 6, n = i & 63;
  float st = expf(log_step[h]);
  st = fminf(fmaxf(st, 1e-5f), 1.0f);
  float lam = -expf(log_neg_real[n]);
  float sre = st * lam;
  float sim = st * imagp[n];
  float bre = B_re[i] * st, bim = B_im[i] * st;
  float cre = C_re[i], cim = C_im[i];
  sre_a[i] = sre;
  sim_a[i] = sim;
  cbr_a[i] = cre * bre - cim * bim;
  cbi_a[i] = cre * bim + cim * bre;
  float pm = expf(64.f * sre);
  z64_a[2 * i]     = pm * cosf(64.f * sim);
  z64_a[2 * i + 1] = pm * sinf(64.f * sim);
}

// setup2: K[h][d] = Re(sum_n CB z^d), d in [0,64)
__global__ __launch_bounds__(256) void setup_k(char* __restrict__ wsb) {
  int i = blockIdx.x * 256 + threadIdx.x;  // h*64+d
  if (i >= H_DIM * 64) return;
  const float* sre_a = (const float*)(wsb + PAR_OFF);
  const float* sim_a = sre_a + 8192;
  const float* cbr_a = sre_a + 16384;
  const float* cbi_a = sre_a + 24576;
  float* kb = (float*)(wsb + KBUF_OFF);
  int h = i >> 6;
  float d = (float)(i & 63);
  float acc = 0.f;
  for (int n = 0; n < 64; ++n) {
    int idx = (h << 6) | n;
    float em = expf(d * sre_a[idx]);
    float ph = d * sim_a[idx];
    acc += cbr_a[idx] * em * cosf(ph) - cbi_a[idx] * em * sinf(ph);
  }
  kb[i] = acc;
}

// setup3: frag-swizzled bf16 tables W_RE/W_IM (A-op), TT/M_RE/M_NIM (B-op).
__global__ __launch_bounds__(256) void setup_tbl(char* __restrict__ wsb) {
  int id = blockIdx.x * 256 + threadIdx.x;  // 65536 total
  const float* sre_a = (const float*)(wsb + PAR_OFF);
  const float* sim_a = sre_a + 8192;
  const float* cbr_a = sre_a + 16384;
  const float* cbi_a = sre_a + 24576;
  const float* kb = (const float*)(wsb + KBUF_OFF);
  unsigned short* tbl = (unsigned short*)(wsb + TBL_OFF);

  int lane = id & 63;
  int kt   = (id >> 6) & 1;
  int blk  = (id >> 7) & 3;
  int h    = id >> 9;
  int lrow = lane & 15, lk = lane >> 4;

  short wre8[8], wim8[8], tt8[8], mre8[8], mni8[8];

  // W: A-operand of S-comp. row n = blk*16+lrow, k t = kt*32+lk*8+j, val z^(63-t)
  {
    int n = blk * 16 + lrow;
    int idx = (h << 6) | n;
    float sre = sre_a[idx], sim = sim_a[idx];
    #pragma unroll
    for (int j = 0; j < 8; ++j) {
      float p = (float)(63 - (kt * 32 + lk * 8 + j));
      float em = expf(p * sre);
      wre8[j] = (short)bfbits(em * cosf(p * sim));
      wim8[j] = (short)bfbits(em * sinf(p * sim));
    }
  }
  // TT: B-operand of conv. col t = blk*16+lrow, k j = kt*32+lk*8+jj, val K[t-j] (t>=j)
  {
    int t = blk * 16 + lrow;
    #pragma unroll
    for (int j = 0; j < 8; ++j) {
      int jj = kt * 32 + lk * 8 + j;
      int d = t - jj;
      tt8[j] = (d >= 0) ? (short)bfbits(kb[(h << 6) | d]) : (short)0;
    }
  }
  // M: B-operand of boundary. col t = blk*16+lrow, k n = kt*32+lk*8+j,
  // val_re = Re(CB z^(t+1)), val_nim = -Im(CB z^(t+1))
  {
    int t = blk * 16 + lrow;
    float p = (float)(t + 1);
    #pragma unroll
    for (int j = 0; j < 8; ++j) {
      int n = kt * 32 + lk * 8 + j;
      int idx = (h << 6) | n;
      float em = expf(p * sre_a[idx]);
      float ph = p * sim_a[idx];
      float zr = em * cosf(ph), zi = em * sinf(ph);
      float cr = cbr_a[idx], ci = cbi_a[idx];
      mre8[j] = (short)bfbits(cr * zr - ci * zi);
      mni8[j] = (short)bfbits(-(cr * zi + ci * zr));
    }
  }
  *(short8*)(tbl + WRE_E  + id * 8) = *(short8*)wre8;
  *(short8*)(tbl + WIM_E  + id * 8) = *(short8*)wim8;
  *(short8*)(tbl + TT_E   + id * 8) = *(short8*)tt8;
  *(short8*)(tbl + MRE_E  + id * 8) = *(short8*)mre8;
  *(short8*)(tbl + MNIM_E + id * 8) = *(short8*)mni8;
}

// (b,l,h) f32 -> (b,h,l) bf16 transpose via LDS 64x64 tiles.
__global__ __launch_bounds__(256) void transpose_u_bf(
    const float* __restrict__ u, unsigned short* __restrict__ ut) {
  __shared__ float tile[64][65];
  int blk = blockIdx.x;            // b*128 + ht*64 + lt
  int b  = blk >> 7;
  int ht = (blk >> 6) & 1;
  int lt = blk & 63;
  int t = threadIdx.x;
  int l0 = lt * 64, h0 = ht * 64;
  #pragma unroll
  for (int p = 0; p < 16; ++p) {
    int ll = p * 4 + (t >> 6);
    int hh = t & 63;
    tile[ll][hh] = u[((size_t)(b * L_SEQ + l0 + ll)) * H_DIM + h0 + hh];
  }
  __syncthreads();
  #pragma unroll
  for (int p = 0; p < 8; ++p) {
    int hh = p * 8 + (t >> 5);
    int l2 = (t & 31) * 2;
    unsigned int lo = bfbits(tile[l2][hh]);
    unsigned int hi = bfbits(tile[l2 + 1][hh]);
    *(unsigned int*)(ut + (((size_t)(b * H_DIM + h0 + hh)) << 12) + l0 + l2)
        = lo | (hi << 16);
  }
}

// Main: per (b,h) block (4 waves). U(64c x 64t) in LDS; S=WxU (MFMA);
// 63-step chunk scan (wave 0); Y = U^T x TT + Xre x M_RE + Xim x M_NIM (MFMA).
// Writes y (bf16) in-place over this block's U region.
__global__ __launch_bounds__(256) void s4d_mfma(
    unsigned short* ut, const unsigned short* __restrict__ tbl,
    const float* __restrict__ z64) {
  __shared__ __align__(16) unsigned short U_lds[64][72];   // [c][t]
  __shared__ float Sre_lds[64][68];                        // [n][c]
  __shared__ float Sim_lds[64][68];
  __shared__ __align__(16) unsigned short Xre_lds[64][72]; // [c][n]
  __shared__ __align__(16) unsigned short Xim_lds[64][72];

  int bidx = blockIdx.x;           // b*128 + h
  int h = bidx & 127;
  int tid = threadIdx.x;
  int w = tid >> 6, lane = tid & 63;
  int lrow = lane & 15, lk = lane >> 4;

  unsigned short* ublk = ut + ((size_t)bidx << 12);

  // stage 0: U fill (linear copy, bf16)
  #pragma unroll
  for (int it = 0; it < 2; ++it) {
    int chunk = it * 256 + tid;            // 0..511, = c*8 + t0/8
    short8 v = *(const short8*)(ublk + chunk * 8);
    *(short8*)&U_lds[chunk >> 3][(chunk & 7) * 8] = v;
  }
  __syncthreads();

  // stage 1: S = W x U   (rows n in [16w,16w+16))
  int wbase = ((h * 4 + w) * 2) * 64 + lane;
  short8 wre0 = *(const short8*)(tbl + WRE_E + (size_t)wbase * 8);
  short8 wre1 = *(const short8*)(tbl + WRE_E + (size_t)(wbase + 64) * 8);
  short8 wim0 = *(const short8*)(tbl + WIM_E + (size_t)wbase * 8);
  short8 wim1 = *(const short8*)(tbl + WIM_E + (size_t)(wbase + 64) * 8);

  f32x4 sacc_re[4], sacc_im[4];
  #pragma unroll
  for (int ct = 0; ct < 4; ++ct) { sacc_re[ct] = (f32x4)0.f; sacc_im[ct] = (f32x4)0.f; }
  #pragma unroll
  for (int ct = 0; ct < 4; ++ct) {
    short8 uf0 = *(const short8*)&U_lds[16 * ct + lrow][lk * 8];
    short8 uf1 = *(const short8*)&U_lds[16 * ct + lrow][32 + lk * 8];
    sacc_re[ct] = mfma16(wre0, uf0, sacc_re[ct]);
    sacc_re[ct] = mfma16(wre1, uf1, sacc_re[ct]);
    sacc_im[ct] = mfma16(wim0, uf0, sacc_im[ct]);
    sacc_im[ct] = mfma16(wim1, uf1, sacc_im[ct]);
  }
  #pragma unroll
  for (int ct = 0; ct < 4; ++ct) {
    #pragma unroll
    for (int r = 0; r < 4; ++r) {
      int n = 16 * w + lk * 4 + r;
      int c = 16 * ct + lrow;
      Sre_lds[n][c] = sacc_re[ct][r];
      Sim_lds[n][c] = sacc_im[ct][r];
    }
  }
  __syncthreads();

  // stage 2: chunk-level scan, wave 0, lane = n. X[c] = z64*X[c-1] + S[c-1], X[0]=0
  if (w == 0) {
    float zr = z64[2 * ((h << 6) | lane)];
    float zi = z64[2 * ((h << 6) | lane) + 1];
    float xr = 0.f, xi = 0.f;
    Xre_lds[0][lane] = 0;
    Xim_lds[0][lane] = 0;
    for (int c = 1; c < 64; ++c) {
      float sr = Sre_lds[lane][c - 1];
      float si = Sim_lds[lane][c - 1];
      float nr = fmaf(zr, xr, fmaf(-zi, xi, sr));
      float ni = fmaf(zr, xi, fmaf(zi, xr, si));
      xr = nr; xi = ni;
      Xre_lds[c][lane] = bfbits(xr);
      Xim_lds[c][lane] = bfbits(xi);
    }
  }
  __syncthreads();

  // stage 3: Y rows c in [16w,16w+16): Y = U^T x TT + Xre x M_RE + Xim x M_NIM
  short8 ua0 = *(const short8*)&U_lds[16 * w + lrow][lk * 8];
  short8 ua1 = *(const short8*)&U_lds[16 * w + lrow][32 + lk * 8];
  short8 xr0 = *(const short8*)&Xre_lds[16 * w + lrow][lk * 8];
  short8 xr1 = *(const short8*)&Xre_lds[16 * w + lrow][32 + lk * 8];
  short8 xi0 = *(const short8*)&Xim_lds[16 * w + lrow][lk * 8];
  short8 xi1 = *(const short8*)&Xim_lds[16 * w + lrow][32 + lk * 8];

  f32x4 yacc[4];
  #pragma unroll
  for (int tt = 0; tt < 4; ++tt) yacc[tt] = (f32x4)0.f;
  #pragma unroll
  for (int tt = 0; tt < 4; ++tt) {
    int tb0 = ((h * 4 + tt) * 2) * 64 + lane;
    int tb1 = tb0 + 64;
    short8 tf0 = *(const short8*)(tbl + TT_E   + (size_t)tb0 * 8);
    short8 tf1 = *(const short8*)(tbl + TT_E   + (size_t)tb1 * 8);
    short8 mr0 = *(const short8*)(tbl + MRE_E  + (size_t)tb0 * 8);
    short8 mr1 = *(const short8*)(tbl + MRE_E  + (size_t)tb1 * 8);
    short8 mn0 = *(const short8*)(tbl + MNIM_E + (size_t)tb0 * 8);
    short8 mn1 = *(const short8*)(tbl + MNIM_E + (size_t)tb1 * 8);
    yacc[tt] = mfma16(ua0, tf0, yacc[tt]);
    yacc[tt] = mfma16(ua1, tf1, yacc[tt]);
    yacc[tt] = mfma16(xr0, mr0, yacc[tt]);
    yacc[tt] = mfma16(xr1, mr1, yacc[tt]);
    yacc[tt] = mfma16(xi0, mn0, yacc[tt]);
    yacc[tt] = mfma16(xi1, mn1, yacc[tt]);
  }
  // store: l = c*64 + t, c = 16w + lk*4 + r, t = 16tt + lrow
  #pragma unroll
  for (int tt = 0; tt < 4; ++tt) {
    #pragma unroll
    for (int r = 0; r < 4; ++r) {
      int c = 16 * w + lk * 4 + r;
      ublk[c * 64 + 16 * tt + lrow] = bfbits(yacc[tt][r]);
    }
  }
}

// post_ln: block = (b, 32-l tile). Load 128h x 32l bf16 conv tile coalesced into
// LDS; per (b,l): add D*u (f32, coalesced), exact GELU, LN over H, coalesced out.
__global__ __launch_bounds__(256) void post_ln_t(
    const unsigned short* __restrict__ ylin, const float* __restrict__ u,
    const float* __restrict__ Dp, const float* __restrict__ gamma,
    const float* __restrict__ beta, float* __restrict__ out) {
  __shared__ float ybuf[H_DIM][33];
  int blk = blockIdx.x;           // b*(L/32) + lt
  int b = blk >> 7;
  int l0 = (blk & 127) * 32;
  int t = threadIdx.x;

  #pragma unroll
  for (int p = 0; p < 4; ++p) {
    int h = p * 32 + (t >> 3);
    int c4 = (t & 7) * 4;
    const unsigned short* src = ylin + (((size_t)(b * H_DIM + h)) << 12) + l0 + c4;
    uint2 v = *(const uint2*)src;   // 4 bf16
    ybuf[h][c4 + 0] = __uint_as_float((v.x & 0xffffu) << 16);
    ybuf[h][c4 + 1] = __uint_as_float(v.x & 0xffff0000u);
    ybuf[h][c4 + 2] = __uint_as_float((v.y & 0xffffu) << 16);
    ybuf[h][c4 + 3] = __uint_as_float(v.y & 0xffff0000u);
  }
  __syncthreads();

  int w = t >> 6, lane = t & 63;
  float2 gm = *(const float2*)(gamma + lane * 2);
  float2 bt = *(const float2*)(beta + lane * 2);
  float2 dd = *(const float2*)(Dp + lane * 2);
  const float kInvSqrt2 = 0.70710678118654752f;
  #pragma unroll 1
  for (int j = 0; j < 8; ++j) {
    int l = w * 8 + j;
    float2 uu = *(const float2*)(u + ((size_t)(b * L_SEQ + l0 + l)) * H_DIM + lane * 2);
    float y0 = fmaf(dd.x, uu.x, ybuf[2 * lane][l]);
    float y1 = fmaf(dd.y, uu.y, ybuf[2 * lane + 1][l]);
    float g0 = 0.5f * y0 * (1.0f + erff(y0 * kInvSqrt2));
    float g1 = 0.5f * y1 * (1.0f + erff(y1 * kInvSqrt2));
    float s  = g0 + g1;
    float ss = fmaf(g0, g0, g1 * g1);
    #pragma unroll
    for (int off = 32; off >= 1; off >>= 1) {
      s  += __shfl_xor(s,  off);
      ss += __shfl_xor(ss, off);
    }
    float mean = s * (1.0f / H_DIM);
    float var  = ss * (1.0f / H_DIM) - mean * mean;
    float inv  = rsqrtf(var + LN_EPS);
    float2 o;
    o.x = (g0 - mean) * inv * gm.x + bt.x;
    o.y = (g1 - mean) * inv * gm.y + bt.y;
    *(float2*)(out + ((size_t)(b * L_SEQ + l0 + l)) * H_DIM + lane * 2) = o;
  }
}

extern "C" void kernel_launch(void* const* d_in, const int* in_sizes, int n_in,
                              void* d_out, int out_size, void* d_ws, size_t ws_size,
                              hipStream_t stream) {
  const float* u     = (const float*)d_in[0];
  const float* lnr   = (const float*)d_in[1];
  const float* im    = (const float*)d_in[2];
  const float* Bre   = (const float*)d_in[3];
  const float* Bim   = (const float*)d_in[4];
  const float* Cre   = (const float*)d_in[5];
  const float* Cim   = (const float*)d_in[6];
  const float* D     = (const float*)d_in[7];
  const float* lstep = (const float*)d_in[8];
  const float* gamma = (const float*)d_in[9];
  const float* beta  = (const float*)d_in[10];
  float* out = (float*)d_out;
  char* wsb  = (char*)d_ws;
  unsigned short* ut  = (unsigned short*)(wsb + UT_OFF);
  const unsigned short* tbl = (const unsigned short*)(wsb + TBL_OFF);
  const float* z64 = (const float*)(wsb + Z64_OFF);

  setup_par<<<32, 256, 0, stream>>>(lnr, im, Bre, Bim, Cre, Cim, lstep, wsb);
  setup_k<<<32, 256, 0, stream>>>(wsb);
  setup_tbl<<<256, 256, 0, stream>>>(wsb);
  transpose_u_bf<<<B_SZ * 2 * (L_SEQ / 64), 256, 0, stream>>>(u, ut);
  s4d_mfma<<<B_SZ * H_DIM, 256, 0, stream>>>(ut, tbl, z64);
  post_ln_t<<<B_SZ * (L_SEQ / 32), 256, 0, stream>>>(ut, u, D, gamma, beta, out);
}

// Round 6
// 127.904 us; speedup vs baseline: 3.7767x; 1.1162x over previous
//
#include <hip/hip_runtime.h>
#include <hip/hip_bf16.h>
#include <math.h>

#define B_SZ 8
#define L_SEQ 4096
#define H_DIM 128
#define N_STATE 64
#define LN_EPS 1e-5f

typedef __attribute__((ext_vector_type(8))) short short8;
typedef __attribute__((ext_vector_type(4))) float f32x4;

// ---------------- ws layout (byte offsets) ----------------
// UT  @ 0       : (b,h,l) bf16, 8 MB (overwritten in-place with ylin by s4d_mfma)
// Z64 @ 8388608 : f32[8192*2]  z^64 (re,im) per (h,n)
// TBL @ 8454144 : 5 bf16 tables, each 524288 ushorts (1 MB), frag-swizzled:
//   entry id = ((h*4 + blk)*2 + kt)*64 + lane, 8 values each (j=0..7)
#define UT_OFF  0
#define Z64_OFF 8388608
#define TBL_OFF 8454144
#define WRE_E   0
#define WIM_E   524288
#define TT_E    1048576
#define MRE_E   1572864
#define MNIM_E  2097152

__device__ __forceinline__ unsigned short bfbits(float f) {
  return __bfloat16_as_ushort(__float2bfloat16(f));
}
__device__ __forceinline__ float bf2f(unsigned short u) {
  return __uint_as_float(((unsigned int)u) << 16);
}
__device__ __forceinline__ f32x4 mfma16(short8 a, short8 b, f32x4 c) {
  return __builtin_amdgcn_mfma_f32_16x16x32_bf16(a, b, c, 0, 0, 0);
}
__device__ __forceinline__ void cmul(float ar, float ai, float br, float bi,
                                     float& cr, float& ci) {
  cr = fmaf(ar, br, -(ai * bi));
  ci = fmaf(ar, bi, ai * br);
}
// z^p, p in [0,127], branch-free binary exponentiation (predicated, no trig)
__device__ __forceinline__ void cpow(float zr, float zi, int p, float& rr, float& ri) {
  float xr = 1.f, xi = 0.f, pr = zr, pi = zi;
  #pragma unroll
  for (int k = 0; k < 7; ++k) {
    if (p & (1 << k)) {
      float a, b2; cmul(xr, xi, pr, pi, a, b2); xr = a; xi = b2;
    }
    float a, b2; cmul(pr, pi, pr, pi, a, b2); pr = a; pi = b2;
  }
  rr = xr; ri = xi;
}

// One block per h: params -> K -> all 5 frag-swizzled tables. Only 64 sincosf
// calls per block (one per n); every power z^p comes from FMA-only cpow.
__global__ __launch_bounds__(256) void setup_all(
    const float* __restrict__ lnr, const float* __restrict__ imp,
    const float* __restrict__ Bre, const float* __restrict__ Bim,
    const float* __restrict__ Cre, const float* __restrict__ Cim,
    const float* __restrict__ lstep, char* __restrict__ wsb) {
  __shared__ float zre_s[64], zim_s[64], cbr_s[64], cbi_s[64], K_s[64];
  int h = blockIdx.x;
  int tid = threadIdx.x;

  if (tid < 64) {
    int n = tid;
    float st = expf(lstep[h]);
    st = fminf(fmaxf(st, 1e-5f), 1.0f);
    float sre = st * (-expf(lnr[n]));
    float sim = st * imp[n];
    float em = expf(sre);
    float sn, cs;
    sincosf(sim, &sn, &cs);                 // the ONLY large-arg trig
    float zr = em * cs, zi = em * sn;
    zre_s[n] = zr; zim_s[n] = zi;
    int i = (h << 6) | n;
    float br = Bre[i] * st, bi = Bim[i] * st;
    float cr = Cre[i], ci = Cim[i];
    cbr_s[n] = cr * br - ci * bi;
    cbi_s[n] = cr * bi + ci * br;
    float wr = zr, wi = zi;                 // z^64 via 6 squarings
    #pragma unroll
    for (int k = 0; k < 6; ++k) { float a, b2; cmul(wr, wi, wr, wi, a, b2); wr = a; wi = b2; }
    float* z64 = (float*)(wsb + Z64_OFF);
    z64[2 * i]     = wr;
    z64[2 * i + 1] = wi;
  }
  __syncthreads();
  if (tid < 64) {
    int d = tid;
    float acc = 0.f;
    for (int n = 0; n < 64; ++n) {
      float pr, pi;
      cpow(zre_s[n], zim_s[n], d, pr, pi);
      acc = fmaf(cbr_s[n], pr, fmaf(-cbi_s[n], pi, acc));
    }
    K_s[d] = acc;
  }
  __syncthreads();

  unsigned short* tbl = (unsigned short*)(wsb + TBL_OFF);
  #pragma unroll
  for (int e = 0; e < 2; ++e) {
    int ent  = e * 256 + tid;               // ((blk*2)+kt)*64 + lane, 512 per h
    int lane = ent & 63;
    int kt   = (ent >> 6) & 1;
    int blk  = ent >> 7;
    int lrow = lane & 15, lk = lane >> 4;
    int id = ((h * 4 + blk) * 2 + kt) * 64 + lane;
    short wre8[8], wim8[8], tt8[8], mre8[8], mni8[8];

    // W: row n = blk*16+lrow, value z^(63-(kt*32+lk*8+j))
    {
      int n = blk * 16 + lrow;
      float zr = zre_s[n], zi = zim_s[n];
      int q0 = 56 - kt * 32 - lk * 8;       // lowest power in the 8-group (>=0)
      float pr, pi;
      cpow(zr, zi, q0, pr, pi);
      #pragma unroll
      for (int jj = 0; jj < 8; ++jj) {      // ascending power q0+jj -> j = 7-jj
        wre8[7 - jj] = (short)bfbits(pr);
        wim8[7 - jj] = (short)bfbits(pi);
        float a, b2; cmul(pr, pi, zr, zi, a, b2); pr = a; pi = b2;
      }
    }
    // TT: col t = blk*16+lrow, k jj = kt*32+lk*8+j, value K[t-jj] (t>=jj)
    {
      int t = blk * 16 + lrow;
      #pragma unroll
      for (int j = 0; j < 8; ++j) {
        int d = t - (kt * 32 + lk * 8 + j);
        tt8[j] = (d >= 0) ? (short)bfbits(K_s[d]) : (short)0;
      }
    }
    // M: col t = blk*16+lrow, k n = kt*32+lk*8+j, value CB_n * z_n^(t+1)
    {
      int t = blk * 16 + lrow;
      #pragma unroll
      for (int j = 0; j < 8; ++j) {
        int n = kt * 32 + lk * 8 + j;
        float pr, pi, vr, vi;
        cpow(zre_s[n], zim_s[n], t + 1, pr, pi);
        cmul(cbr_s[n], cbi_s[n], pr, pi, vr, vi);
        mre8[j] = (short)bfbits(vr);
        mni8[j] = (short)bfbits(-vi);
      }
    }
    *(short8*)(tbl + WRE_E  + (size_t)id * 8) = *(short8*)wre8;
    *(short8*)(tbl + WIM_E  + (size_t)id * 8) = *(short8*)wim8;
    *(short8*)(tbl + TT_E   + (size_t)id * 8) = *(short8*)tt8;
    *(short8*)(tbl + MRE_E  + (size_t)id * 8) = *(short8*)mre8;
    *(short8*)(tbl + MNIM_E + (size_t)id * 8) = *(short8*)mni8;
  }
}

// (b,l,h) f32 -> (b,h,l) bf16 transpose via LDS 64x64 tiles.
__global__ __launch_bounds__(256) void transpose_u_bf(
    const float* __restrict__ u, unsigned short* __restrict__ ut) {
  __shared__ float tile[64][65];
  int blk = blockIdx.x;            // b*128 + ht*64 + lt
  int b  = blk >> 7;
  int ht = (blk >> 6) & 1;
  int lt = blk & 63;
  int t = threadIdx.x;
  int l0 = lt * 64, h0 = ht * 64;
  #pragma unroll
  for (int p = 0; p < 16; ++p) {
    int ll = p * 4 + (t >> 6);
    int hh = t & 63;
    tile[ll][hh] = u[((size_t)(b * L_SEQ + l0 + ll)) * H_DIM + h0 + hh];
  }
  __syncthreads();
  #pragma unroll
  for (int p = 0; p < 8; ++p) {
    int hh = p * 8 + (t >> 5);
    int l2 = (t & 31) * 2;
    unsigned int lo = bfbits(tile[l2][hh]);
    unsigned int hi = bfbits(tile[l2 + 1][hh]);
    *(unsigned int*)(ut + (((size_t)(b * H_DIM + h0 + hh)) << 12) + l0 + l2)
        = lo | (hi << 16);
  }
}

// Per (b,h) block, 4 waves. U in LDS; S = W x U (MFMA, bf16 S);
// per-wave redundant chunk scan (wave w writes X rows [16w,16w+16) only ->
// no barrier before stage 3); Y = U^T x TT + Xre x M_RE + Xim x M_NIM + D*u.
// LDS 44.5 KB -> 3 blocks/CU.
__global__ __launch_bounds__(256) void s4d_mfma(
    unsigned short* ut, const unsigned short* __restrict__ tbl,
    const float* __restrict__ z64, const float* __restrict__ Dp) {
  __shared__ __align__(16) unsigned short U_lds[64][72];    // [c][t]
  __shared__ unsigned short Sre_lds[64][66];                // [n][c] bf16
  __shared__ unsigned short Sim_lds[64][66];
  __shared__ __align__(16) unsigned short Xre_lds[64][72];  // [c][n]
  __shared__ __align__(16) unsigned short Xim_lds[64][72];

  int bidx = blockIdx.x;           // b*128 + h
  int h = bidx & 127;
  int tid = threadIdx.x;
  int w = tid >> 6, lane = tid & 63;
  int lrow = lane & 15, lk = lane >> 4;
  unsigned short* ublk = ut + ((size_t)bidx << 12);
  float Dh = Dp[h];

  // stage 0: U fill (linear bf16 copy)
  #pragma unroll
  for (int it = 0; it < 2; ++it) {
    int chunk = it * 256 + tid;            // c*8 + t0/8
    short8 v = *(const short8*)(ublk + chunk * 8);
    *(short8*)&U_lds[chunk >> 3][(chunk & 7) * 8] = v;
  }
  __syncthreads();

  // stage 1: S = W x U  (rows n in [16w,16w+16))
  int wbase = ((h * 4 + w) * 2) * 64 + lane;
  short8 wre0 = *(const short8*)(tbl + WRE_E + (size_t)wbase * 8);
  short8 wre1 = *(const short8*)(tbl + WRE_E + (size_t)(wbase + 64) * 8);
  short8 wim0 = *(const short8*)(tbl + WIM_E + (size_t)wbase * 8);
  short8 wim1 = *(const short8*)(tbl + WIM_E + (size_t)(wbase + 64) * 8);

  f32x4 sacc_re[4], sacc_im[4];
  #pragma unroll
  for (int ct = 0; ct < 4; ++ct) { sacc_re[ct] = (f32x4)0.f; sacc_im[ct] = (f32x4)0.f; }
  #pragma unroll
  for (int ct = 0; ct < 4; ++ct) {
    short8 uf0 = *(const short8*)&U_lds[16 * ct + lrow][lk * 8];
    short8 uf1 = *(const short8*)&U_lds[16 * ct + lrow][32 + lk * 8];
    sacc_re[ct] = mfma16(wre0, uf0, sacc_re[ct]);
    sacc_re[ct] = mfma16(wre1, uf1, sacc_re[ct]);
    sacc_im[ct] = mfma16(wim0, uf0, sacc_im[ct]);
    sacc_im[ct] = mfma16(wim1, uf1, sacc_im[ct]);
  }
  #pragma unroll
  for (int ct = 0; ct < 4; ++ct) {
    #pragma unroll
    for (int r = 0; r < 4; ++r) {
      int n = 16 * w + lk * 4 + r;
      int c = 16 * ct + lrow;
      Sre_lds[n][c] = bfbits(sacc_re[ct][r]);
      Sim_lds[n][c] = bfbits(sacc_im[ct][r]);
    }
  }
  __syncthreads();

  // stage 2: redundant per-wave chunk scan. X[c] = z64*X[c-1] + S[c-1], X[0]=0.
  // Wave w writes only rows c in [16w,16w+16) -> stage 3 reads are same-wave.
  {
    int gi = (h << 6) | lane;              // lane = state n
    float zr = z64[2 * gi], zi = z64[2 * gi + 1];
    float xr = 0.f, xi = 0.f;
    int clo = 16 * w, chi = 16 * w + 16;
    for (int c = 0; c < chi; ++c) {
      if (c >= clo) {
        Xre_lds[c][lane] = bfbits(xr);
        Xim_lds[c][lane] = bfbits(xi);
      }
      float sr_ = bf2f(Sre_lds[lane][c]);
      float si_ = bf2f(Sim_lds[lane][c]);
      float nr = fmaf(zr, xr, fmaf(-zi, xi, sr_));
      float ni = fmaf(zr, xi, fmaf(zi, xr, si_));
      xr = nr; xi = ni;
    }
  }
  // no barrier: stage 3 only touches this wave's X rows (same-wave DS order)

  // stage 3: Y rows c in [16w,16w+16)
  short8 ua0 = *(const short8*)&U_lds[16 * w + lrow][lk * 8];
  short8 ua1 = *(const short8*)&U_lds[16 * w + lrow][32 + lk * 8];
  short8 xr0 = *(const short8*)&Xre_lds[16 * w + lrow][lk * 8];
  short8 xr1 = *(const short8*)&Xre_lds[16 * w + lrow][32 + lk * 8];
  short8 xi0 = *(const short8*)&Xim_lds[16 * w + lrow][lk * 8];
  short8 xi1 = *(const short8*)&Xim_lds[16 * w + lrow][32 + lk * 8];

  f32x4 yacc[4];
  #pragma unroll
  for (int tt = 0; tt < 4; ++tt) yacc[tt] = (f32x4)0.f;
  #pragma unroll
  for (int tt = 0; tt < 4; ++tt) {
    int tb0 = ((h * 4 + tt) * 2) * 64 + lane;
    int tb1 = tb0 + 64;
    short8 tf0 = *(const short8*)(tbl + TT_E   + (size_t)tb0 * 8);
    short8 tf1 = *(const short8*)(tbl + TT_E   + (size_t)tb1 * 8);
    short8 mr0 = *(const short8*)(tbl + MRE_E  + (size_t)tb0 * 8);
    short8 mr1 = *(const short8*)(tbl + MRE_E  + (size_t)tb1 * 8);
    short8 mn0 = *(const short8*)(tbl + MNIM_E + (size_t)tb0 * 8);
    short8 mn1 = *(const short8*)(tbl + MNIM_E + (size_t)tb1 * 8);
    yacc[tt] = mfma16(ua0, tf0, yacc[tt]);
    yacc[tt] = mfma16(ua1, tf1, yacc[tt]);
    yacc[tt] = mfma16(xr0, mr0, yacc[tt]);
    yacc[tt] = mfma16(xr1, mr1, yacc[tt]);
    yacc[tt] = mfma16(xi0, mn0, yacc[tt]);
    yacc[tt] = mfma16(xi1, mn1, yacc[tt]);
  }
  // add D*u (u already in LDS) and store: l = c*64 + t
  #pragma unroll
  for (int tt = 0; tt < 4; ++tt) {
    #pragma unroll
    for (int r = 0; r < 4; ++r) {
      int c = 16 * w + lk * 4 + r;
      int t = 16 * tt + lrow;
      float y = fmaf(Dh, bf2f(U_lds[c][t]), yacc[tt][r]);
      ublk[c * 64 + t] = bfbits(y);
    }
  }
}

// post_ln: block = (b, 32-l tile). Load 128h x 32l bf16 y tile coalesced into
// LDS; per (b,l): exact GELU, LN over H, coalesced f32 out. No u re-read.
__global__ __launch_bounds__(256) void post_ln_t(
    const unsigned short* __restrict__ ylin, const float* __restrict__ gamma,
    const float* __restrict__ beta, float* __restrict__ out) {
  __shared__ float ybuf[H_DIM][33];
  int blk = blockIdx.x;           // b*(L/32) + lt
  int b = blk >> 7;
  int l0 = (blk & 127) * 32;
  int t = threadIdx.x;

  #pragma unroll
  for (int p = 0; p < 4; ++p) {
    int h = p * 32 + (t >> 3);
    int c4 = (t & 7) * 4;
    const unsigned short* src = ylin + (((size_t)(b * H_DIM + h)) << 12) + l0 + c4;
    uint2 v = *(const uint2*)src;   // 4 bf16
    ybuf[h][c4 + 0] = __uint_as_float((v.x & 0xffffu) << 16);
    ybuf[h][c4 + 1] = __uint_as_float(v.x & 0xffff0000u);
    ybuf[h][c4 + 2] = __uint_as_float((v.y & 0xffffu) << 16);
    ybuf[h][c4 + 3] = __uint_as_float(v.y & 0xffff0000u);
  }
  __syncthreads();

  int w = t >> 6, lane = t & 63;
  float2 gm = *(const float2*)(gamma + lane * 2);
  float2 bt = *(const float2*)(beta + lane * 2);
  const float kInvSqrt2 = 0.70710678118654752f;
  #pragma unroll 1
  for (int j = 0; j < 8; ++j) {
    int l = w * 8 + j;
    float y0 = ybuf[2 * lane][l];
    float y1 = ybuf[2 * lane + 1][l];
    float g0 = 0.5f * y0 * (1.0f + erff(y0 * kInvSqrt2));
    float g1 = 0.5f * y1 * (1.0f + erff(y1 * kInvSqrt2));
    float s  = g0 + g1;
    float ss = fmaf(g0, g0, g1 * g1);
    #pragma unroll
    for (int off = 32; off >= 1; off >>= 1) {
      s  += __shfl_xor(s,  off);
      ss += __shfl_xor(ss, off);
    }
    float mean = s * (1.0f / H_DIM);
    float var  = ss * (1.0f / H_DIM) - mean * mean;
    float inv  = rsqrtf(var + LN_EPS);
    float2 o;
    o.x = (g0 - mean) * inv * gm.x + bt.x;
    o.y = (g1 - mean) * inv * gm.y + bt.y;
    *(float2*)(out + ((size_t)(b * L_SEQ + l0 + l)) * H_DIM + lane * 2) = o;
  }
}

extern "C" void kernel_launch(void* const* d_in, const int* in_sizes, int n_in,
                              void* d_out, int out_size, void* d_ws, size_t ws_size,
                              hipStream_t stream) {
  const float* u     = (const float*)d_in[0];
  const float* lnr   = (const float*)d_in[1];
  const float* im    = (const float*)d_in[2];
  const float* Bre   = (const float*)d_in[3];
  const float* Bim   = (const float*)d_in[4];
  const float* Cre   = (const float*)d_in[5];
  const float* Cim   = (const float*)d_in[6];
  const float* D     = (const float*)d_in[7];
  const float* lstep = (const float*)d_in[8];
  const float* gamma = (const float*)d_in[9];
  const float* beta  = (const float*)d_in[10];
  float* out = (float*)d_out;
  char* wsb  = (char*)d_ws;
  unsigned short* ut  = (unsigned short*)(wsb + UT_OFF);
  const unsigned short* tbl = (const unsigned short*)(wsb + TBL_OFF);
  const float* z64 = (const float*)(wsb + Z64_OFF);

  setup_all<<<H_DIM, 256, 0, stream>>>(lnr, im, Bre, Bim, Cre, Cim, lstep, wsb);
  transpose_u_bf<<<B_SZ * 2 * (L_SEQ / 64), 256, 0, stream>>>(u, ut);
  s4d_mfma<<<B_SZ * H_DIM, 256, 0, stream>>>(ut, tbl, z64, D);
  post_ln_t<<<B_SZ * (L_SEQ / 32), 256, 0, stream>>>(ut, gamma, beta, out);
}

// Round 7
// 105.849 us; speedup vs baseline: 4.5637x; 1.2084x over previous
//
#include <hip/hip_runtime.h>
#include <hip/hip_bf16.h>
#include <math.h>

#define B_SZ 8
#define L_SEQ 4096
#define H_DIM 128
#define LN_EPS 1e-5f

typedef __attribute__((ext_vector_type(8))) short short8;
typedef __attribute__((ext_vector_type(4))) float f32x4;

// ---------------- ws layout (byte offsets) ----------------
// UT  @ 0       : (b,h,l) bf16, 8 MB (overwritten in-place with ylin by s4d_mfma)
// Z64 @ 8388608 : f32[8192*2]  z^64 (re,im) per (h,n)
// TBL @ 8454144 : 5 bf16 tables, each 524288 ushorts, frag-swizzled:
//   entry id = ((h*4 + blk)*2 + kt)*64 + lane, 8 values each
#define UT_OFF  0
#define Z64_OFF 8388608
#define TBL_OFF 8454144
#define WRE_E   0
#define WIM_E   524288
#define TT_E    1048576
#define MRE_E   1572864
#define MNIM_E  2097152

__device__ __forceinline__ unsigned short bfbits(float f) {
  return __bfloat16_as_ushort(__float2bfloat16(f));
}
__device__ __forceinline__ float lo2f(unsigned int v) {
  return __uint_as_float((v & 0xffffu) << 16);
}
__device__ __forceinline__ float hi2f(unsigned int v) {
  return __uint_as_float(v & 0xffff0000u);
}
__device__ __forceinline__ float bf2f(unsigned short u) {
  return __uint_as_float(((unsigned int)u) << 16);
}
__device__ __forceinline__ f32x4 mfma16(short8 a, short8 b, f32x4 c) {
  return __builtin_amdgcn_mfma_f32_16x16x32_bf16(a, b, c, 0, 0, 0);
}
__device__ __forceinline__ void cmul(float ar, float ai, float br, float bi,
                                     float& cr, float& ci) {
  cr = fmaf(ar, br, -(ai * bi));
  ci = fmaf(ar, bi, ai * br);
}
__device__ __forceinline__ void cpow(float zr, float zi, int p, float& rr, float& ri) {
  float xr = 1.f, xi = 0.f, pr = zr, pi = zi;
  #pragma unroll
  for (int k = 0; k < 7; ++k) {
    if (p & (1 << k)) { float a, b; cmul(xr, xi, pr, pi, a, b); xr = a; xi = b; }
    float a, b; cmul(pr, pi, pr, pi, a, b); pr = a; pi = b;
  }
  rr = xr; ri = xi;
}

struct PrepShared {
  union {
    float tile[64][65];
    unsigned int zp[64][65];   // packed bf16 (lo=re, hi=im); zp[n][p], p in [0,64]
  } uu;
  float zre[64], zim[64], cbr[64], cbi[64], K[64];
};

// one 64x64 (b,l,h)->(b,h,l) transpose tile; leading barrier protects LDS reuse
__device__ __forceinline__ void transpose_tile(
    const float* __restrict__ u, unsigned short* __restrict__ ut,
    int tile_idx, int t, float (*tile)[65]) {
  __syncthreads();
  int b  = tile_idx >> 7;
  int ht = (tile_idx >> 6) & 1;
  int lt = tile_idx & 63;
  int l0 = lt * 64, h0 = ht * 64;
  #pragma unroll
  for (int p = 0; p < 16; ++p) {
    int ll = p * 4 + (t >> 6);
    int hh = t & 63;
    tile[ll][hh] = u[((size_t)(b * L_SEQ + l0 + ll)) * H_DIM + h0 + hh];
  }
  __syncthreads();
  #pragma unroll
  for (int p = 0; p < 8; ++p) {
    int hh = p * 8 + (t >> 5);
    int l2 = (t & 31) * 2;
    unsigned int lo = bfbits(tile[l2][hh]);
    unsigned int hi = bfbits(tile[l2 + 1][hh]);
    *(unsigned int*)(ut + (((size_t)(b * H_DIM + h0 + hh)) << 12) + l0 + l2)
        = lo | (hi << 16);
  }
}

// prep: blocks 0..127 -> per-h table setup (z^p LDS table, no long pow chains);
//       blocks 128..1023 -> transpose tiles (first 128 of them take two tiles).
__global__ __launch_bounds__(256) void prep(
    const float* __restrict__ u, unsigned short* __restrict__ ut,
    const float* __restrict__ lnr, const float* __restrict__ imp,
    const float* __restrict__ Bre, const float* __restrict__ Bim,
    const float* __restrict__ Cre, const float* __restrict__ Cim,
    const float* __restrict__ Dp, const float* __restrict__ lstep,
    char* __restrict__ wsb) {
  __shared__ PrepShared sm;
  int blk = blockIdx.x;
  int tid = threadIdx.x;

  if (blk >= 128) {
    transpose_tile(u, ut, blk - 128, tid, sm.uu.tile);
    if (blk < 256) transpose_tile(u, ut, blk + 768, tid, sm.uu.tile);
    return;
  }

  int h = blk;
  if (tid < 64) {
    int n = tid;
    float st = expf(lstep[h]);
    st = fminf(fmaxf(st, 1e-5f), 1.0f);
    float sre = st * (-expf(lnr[n]));
    float sim = st * imp[n];
    float em = expf(sre);
    float sn, cs;
    sincosf(sim, &sn, &cs);
    float zr = em * cs, zi = em * sn;
    sm.zre[n] = zr; sm.zim[n] = zi;
    int i = (h << 6) | n;
    float br = Bre[i] * st, bi = Bim[i] * st;
    float cr = Cre[i], ci = Cim[i];
    sm.cbr[n] = cr * br - ci * bi;
    sm.cbi[n] = cr * bi + ci * br;
    float wr = zr, wi = zi;                 // z^64 via 6 squarings
    #pragma unroll
    for (int k = 0; k < 6; ++k) { float a, b; cmul(wr, wi, wr, wi, a, b); wr = a; wi = b; }
    float* z64 = (float*)(wsb + Z64_OFF);
    z64[2 * i]     = wr;
    z64[2 * i + 1] = wi;
  }
  __syncthreads();
  // zp[n][p] = bf16-packed z_n^p, p in [0,64]; thread (n, quarter j)
  {
    int n = tid & 63, j = tid >> 6;
    float zr = sm.zre[n], zi = sm.zim[n];
    float pr, pi;
    cpow(zr, zi, 16 * j, pr, pi);
    int dend = (j == 3) ? 65 : 16 * (j + 1);
    for (int d = 16 * j; d < dend; ++d) {
      sm.uu.zp[n][d] = (unsigned int)bfbits(pr) | ((unsigned int)bfbits(pi) << 16);
      float a, b; cmul(pr, pi, zr, zi, a, b); pr = a; pi = b;
    }
  }
  __syncthreads();
  if (tid < 64) {
    int d = tid;
    float acc = 0.f;
    for (int n = 0; n < 64; ++n) {
      unsigned int v = sm.uu.zp[n][d];
      acc = fmaf(sm.cbr[n], lo2f(v), fmaf(-sm.cbi[n], hi2f(v), acc));
    }
    sm.K[d] = acc;
  }
  __syncthreads();

  float Dh = Dp[h];
  unsigned short* tbl = (unsigned short*)(wsb + TBL_OFF);
  #pragma unroll
  for (int e = 0; e < 2; ++e) {
    int ent  = e * 256 + tid;               // 512 entries per h
    int lane = ent & 63;
    int kt   = (ent >> 6) & 1;
    int blkq = ent >> 7;
    int lrow = lane & 15, lk = lane >> 4;
    int id = ((h * 4 + blkq) * 2 + kt) * 64 + lane;
    short wre8[8], wim8[8], tt8[8], mre8[8], mni8[8];

    // W: row n = blkq*16+lrow, value z^(63-(kt*32+lk*8+j)) — direct zp lookup
    {
      int n = blkq * 16 + lrow;
      #pragma unroll
      for (int j = 0; j < 8; ++j) {
        unsigned int v = sm.uu.zp[n][63 - (kt * 32 + lk * 8 + j)];
        wre8[j] = (short)(v & 0xffffu);
        wim8[j] = (short)(v >> 16);
      }
    }
    // TT: col t = blkq*16+lrow, value K[t-jj] (+D on the diagonal)
    {
      int t = blkq * 16 + lrow;
      #pragma unroll
      for (int j = 0; j < 8; ++j) {
        int d = t - (kt * 32 + lk * 8 + j);
        float kv = (d >= 0) ? (sm.K[d] + ((d == 0) ? Dh : 0.f)) : 0.f;
        tt8[j] = (d >= 0) ? (short)bfbits(kv) : (short)0;
      }
    }
    // M: col t = blkq*16+lrow, value CB_n * z_n^(t+1)
    {
      int t = blkq * 16 + lrow;
      #pragma unroll
      for (int j = 0; j < 8; ++j) {
        int n = kt * 32 + lk * 8 + j;
        unsigned int v = sm.uu.zp[n][t + 1];
        float vr, vi;
        cmul(sm.cbr[n], sm.cbi[n], lo2f(v), hi2f(v), vr, vi);
        mre8[j] = (short)bfbits(vr);
        mni8[j] = (short)bfbits(-vi);
      }
    }
    *(short8*)(tbl + WRE_E  + (size_t)id * 8) = *(short8*)wre8;
    *(short8*)(tbl + WIM_E  + (size_t)id * 8) = *(short8*)wim8;
    *(short8*)(tbl + TT_E   + (size_t)id * 8) = *(short8*)tt8;
    *(short8*)(tbl + MRE_E  + (size_t)id * 8) = *(short8*)mre8;
    *(short8*)(tbl + MNIM_E + (size_t)id * 8) = *(short8*)mni8;
  }
}

// Per (b,h) block, 4 waves, LDS 34.5 KB -> 4 blocks/CU (no tail round).
// Xre aliases the dead U buffer; D is baked into TT's diagonal.
__global__ __launch_bounds__(256, 4) void s4d_mfma(
    unsigned short* ut, const unsigned short* __restrict__ tbl,
    const float* __restrict__ z64) {
  __shared__ __align__(16) unsigned short A_lds[64][72];   // U, then Xre
  __shared__ unsigned short Sre_lds[64][66];               // [n][c] bf16
  __shared__ unsigned short Sim_lds[64][66];
  __shared__ __align__(16) unsigned short Xim_lds[64][72]; // [c][n]

  int bidx = blockIdx.x;           // b*128 + h
  int h = bidx & 127;
  int tid = threadIdx.x;
  int w = tid >> 6, lane = tid & 63;
  int lrow = lane & 15, lk = lane >> 4;
  unsigned short* ublk = ut + ((size_t)bidx << 12);

  // stage 0: U fill
  #pragma unroll
  for (int it = 0; it < 2; ++it) {
    int chunk = it * 256 + tid;
    short8 v = *(const short8*)(ublk + chunk * 8);
    *(short8*)&A_lds[chunk >> 3][(chunk & 7) * 8] = v;
  }
  __syncthreads();

  // stage 1: S = W x U; capture this wave's U A-frags for stage 3
  int wbase = ((h * 4 + w) * 2) * 64 + lane;
  short8 wre0 = *(const short8*)(tbl + WRE_E + (size_t)wbase * 8);
  short8 wre1 = *(const short8*)(tbl + WRE_E + (size_t)(wbase + 64) * 8);
  short8 wim0 = *(const short8*)(tbl + WIM_E + (size_t)wbase * 8);
  short8 wim1 = *(const short8*)(tbl + WIM_E + (size_t)(wbase + 64) * 8);

  f32x4 sacc_re[4], sacc_im[4];
  #pragma unroll
  for (int ct = 0; ct < 4; ++ct) { sacc_re[ct] = (f32x4)0.f; sacc_im[ct] = (f32x4)0.f; }
  short8 ua0 = {}, ua1 = {};
  #pragma unroll
  for (int ct = 0; ct < 4; ++ct) {
    short8 uf0 = *(const short8*)&A_lds[16 * ct + lrow][lk * 8];
    short8 uf1 = *(const short8*)&A_lds[16 * ct + lrow][32 + lk * 8];
    if (ct == w) { ua0 = uf0; ua1 = uf1; }
    sacc_re[ct] = mfma16(wre0, uf0, sacc_re[ct]);
    sacc_re[ct] = mfma16(wre1, uf1, sacc_re[ct]);
    sacc_im[ct] = mfma16(wim0, uf0, sacc_im[ct]);
    sacc_im[ct] = mfma16(wim1, uf1, sacc_im[ct]);
  }
  #pragma unroll
  for (int ct = 0; ct < 4; ++ct) {
    #pragma unroll
    for (int r = 0; r < 4; ++r) {
      int n = 16 * w + lk * 4 + r;
      int c = 16 * ct + lrow;
      Sre_lds[n][c] = bfbits(sacc_re[ct][r]);
      Sim_lds[n][c] = bfbits(sacc_im[ct][r]);
    }
  }
  __syncthreads();   // also: last touch of U in A_lds

  // stage 2: redundant per-wave chunk scan; wave w writes X rows [16w,16w+16)
  {
    int gi = (h << 6) | lane;
    float zr = z64[2 * gi], zi = z64[2 * gi + 1];
    float xr = 0.f, xi = 0.f;
    int clo = 16 * w;
    #pragma unroll 4
    for (int c = 0; c < clo; ++c) {
      float sr_ = bf2f(Sre_lds[lane][c]);
      float si_ = bf2f(Sim_lds[lane][c]);
      float nr = fmaf(zr, xr, fmaf(-zi, xi, sr_));
      float ni = fmaf(zr, xi, fmaf(zi, xr, si_));
      xr = nr; xi = ni;
    }
    #pragma unroll
    for (int k = 0; k < 16; ++k) {
      int c = clo + k;
      A_lds[c][lane]   = bfbits(xr);       // Xre over old U
      Xim_lds[c][lane] = bfbits(xi);
      float sr_ = bf2f(Sre_lds[lane][c]);
      float si_ = bf2f(Sim_lds[lane][c]);
      float nr = fmaf(zr, xr, fmaf(-zi, xi, sr_));
      float ni = fmaf(zr, xi, fmaf(zi, xr, si_));
      xr = nr; xi = ni;
    }
  }
  // no barrier: stage 3 reads only this wave's X rows

  // stage 3: Y rows c in [16w,16w+16): U^T x TT(+D diag) + Xre x M_RE + Xim x M_NIM
  short8 xr0 = *(const short8*)&A_lds[16 * w + lrow][lk * 8];
  short8 xr1 = *(const short8*)&A_lds[16 * w + lrow][32 + lk * 8];
  short8 xi0 = *(const short8*)&Xim_lds[16 * w + lrow][lk * 8];
  short8 xi1 = *(const short8*)&Xim_lds[16 * w + lrow][32 + lk * 8];

  f32x4 yacc[4];
  #pragma unroll
  for (int tt = 0; tt < 4; ++tt) yacc[tt] = (f32x4)0.f;
  #pragma unroll
  for (int tt = 0; tt < 4; ++tt) {
    int tb0 = ((h * 4 + tt) * 2) * 64 + lane;
    int tb1 = tb0 + 64;
    short8 tf0 = *(const short8*)(tbl + TT_E   + (size_t)tb0 * 8);
    short8 tf1 = *(const short8*)(tbl + TT_E   + (size_t)tb1 * 8);
    short8 mr0 = *(const short8*)(tbl + MRE_E  + (size_t)tb0 * 8);
    short8 mr1 = *(const short8*)(tbl + MRE_E  + (size_t)tb1 * 8);
    short8 mn0 = *(const short8*)(tbl + MNIM_E + (size_t)tb0 * 8);
    short8 mn1 = *(const short8*)(tbl + MNIM_E + (size_t)tb1 * 8);
    yacc[tt] = mfma16(ua0, tf0, yacc[tt]);
    yacc[tt] = mfma16(ua1, tf1, yacc[tt]);
    yacc[tt] = mfma16(xr0, mr0, yacc[tt]);
    yacc[tt] = mfma16(xr1, mr1, yacc[tt]);
    yacc[tt] = mfma16(xi0, mn0, yacc[tt]);
    yacc[tt] = mfma16(xi1, mn1, yacc[tt]);
  }
  #pragma unroll
  for (int tt = 0; tt < 4; ++tt) {
    #pragma unroll
    for (int r = 0; r < 4; ++r) {
      int c = 16 * w + lk * 4 + r;
      int t = 16 * tt + lrow;
      ublk[c * 64 + t] = bfbits(yacc[tt][r]);
    }
  }
}

// post_ln: 16-lane group per l-row; 8 h per lane via 2x ds_read_b128;
// 4-stage shuffle reduce (16 shuffles/thread total, was 96).
__global__ __launch_bounds__(256) void post_ln_t(
    const unsigned short* __restrict__ ylin, const float* __restrict__ gamma,
    const float* __restrict__ beta, float* __restrict__ out) {
  __shared__ float ybuf[32][132];    // [l][h], row stride 528 B (16B-aligned)
  int blk = blockIdx.x;              // b*(L/32) + lt
  int b = blk >> 7;
  int l0 = (blk & 127) * 32;
  int t = threadIdx.x;
  const float kInvSqrt2 = 0.70710678118654752f;

  #pragma unroll
  for (int p = 0; p < 4; ++p) {
    int h = p * 32 + (t >> 3);
    int c4 = (t & 7) * 4;
    const unsigned short* src = ylin + (((size_t)(b * H_DIM + h)) << 12) + l0 + c4;
    uint2 v = *(const uint2*)src;    // 4 bf16 (4 consecutive l)
    float y0 = __uint_as_float((v.x & 0xffffu) << 16);
    float y1 = __uint_as_float(v.x & 0xffff0000u);
    float y2 = __uint_as_float((v.y & 0xffffu) << 16);
    float y3 = __uint_as_float(v.y & 0xffff0000u);
    ybuf[c4 + 0][h] = 0.5f * y0 * (1.0f + erff(y0 * kInvSqrt2));
    ybuf[c4 + 1][h] = 0.5f * y1 * (1.0f + erff(y1 * kInvSqrt2));
    ybuf[c4 + 2][h] = 0.5f * y2 * (1.0f + erff(y2 * kInvSqrt2));
    ybuf[c4 + 3][h] = 0.5f * y3 * (1.0f + erff(y3 * kInvSqrt2));
  }
  __syncthreads();

  int slot = t >> 4;                 // 16 groups, 2 l each
  int i = t & 15;                    // lane-in-group: h = 8i..8i+7
  f32x4 gm0 = *(const f32x4*)(gamma + 8 * i);
  f32x4 gm1 = *(const f32x4*)(gamma + 8 * i + 4);
  f32x4 bt0 = *(const f32x4*)(beta + 8 * i);
  f32x4 bt1 = *(const f32x4*)(beta + 8 * i + 4);
  #pragma unroll
  for (int q = 0; q < 2; ++q) {
    int l = slot * 2 + q;
    f32x4 a = *(const f32x4*)&ybuf[l][8 * i];
    f32x4 c = *(const f32x4*)&ybuf[l][8 * i + 4];
    float s  = (a[0] + a[1]) + (a[2] + a[3]) + (c[0] + c[1]) + (c[2] + c[3]);
    float ss = a[0]*a[0] + a[1]*a[1] + a[2]*a[2] + a[3]*a[3]
             + c[0]*c[0] + c[1]*c[1] + c[2]*c[2] + c[3]*c[3];
    #pragma unroll
    for (int off = 8; off >= 1; off >>= 1) {
      s  += __shfl_xor(s,  off);
      ss += __shfl_xor(ss, off);
    }
    float mean = s * (1.0f / H_DIM);
    float var  = ss * (1.0f / H_DIM) - mean * mean;
    float inv  = rsqrtf(var + LN_EPS);
    f32x4 o0, o1;
    #pragma unroll
    for (int k = 0; k < 4; ++k) {
      o0[k] = (a[k] - mean) * inv * gm0[k] + bt0[k];
      o1[k] = (c[k] - mean) * inv * gm1[k] + bt1[k];
    }
    float* dst = out + ((size_t)(b * L_SEQ + l0 + l)) * H_DIM + 8 * i;
    *(f32x4*)dst       = o0;
    *(f32x4*)(dst + 4) = o1;
  }
}

extern "C" void kernel_launch(void* const* d_in, const int* in_sizes, int n_in,
                              void* d_out, int out_size, void* d_ws, size_t ws_size,
                              hipStream_t stream) {
  const float* u     = (const float*)d_in[0];
  const float* lnr   = (const float*)d_in[1];
  const float* im    = (const float*)d_in[2];
  const float* Bre   = (const float*)d_in[3];
  const float* Bim   = (const float*)d_in[4];
  const float* Cre   = (const float*)d_in[5];
  const float* Cim   = (const float*)d_in[6];
  const float* D     = (const float*)d_in[7];
  const float* lstep = (const float*)d_in[8];
  const float* gamma = (const float*)d_in[9];
  const float* beta  = (const float*)d_in[10];
  float* out = (float*)d_out;
  char* wsb  = (char*)d_ws;
  unsigned short* ut  = (unsigned short*)(wsb + UT_OFF);
  const unsigned short* tbl = (const unsigned short*)(wsb + TBL_OFF);
  const float* z64 = (const float*)(wsb + Z64_OFF);

  prep<<<1024, 256, 0, stream>>>(u, ut, lnr, im, Bre, Bim, Cre, Cim, D, lstep, wsb);
  s4d_mfma<<<1024, 256, 0, stream>>>(ut, tbl, z64);
  post_ln_t<<<1024, 256, 0, stream>>>(ut, gamma, beta, out);
}